// Round 1
// baseline (1288.887 us; speedup 1.0000x reference)
//
#include <hip/hip_runtime.h>
#include <hip/hip_bf16.h>
#include <math.h>

#define N_NODES 50000
#define N_EDGES 800000
#define BB 2
#define WFEAT 128
#define DD 64
#define OUTD 128

// ---------------- Kernel 1: node projections e_q = emb @ Wq^T, e_k = emb @ Wk^T
__global__ void proj_kernel(const float* __restrict__ emb,
                            const float* __restrict__ Wq,
                            const float* __restrict__ Wk,
                            float* __restrict__ eq, float* __restrict__ ek) {
    int t = blockIdx.x * blockDim.x + threadIdx.x;   // over N*D
    if (t >= N_NODES * DD) return;
    int n = t >> 6, d = t & 63;
    const float* er = emb + (size_t)n * DD;
    const float* wq = Wq + (size_t)d * DD;
    const float* wk = Wk + (size_t)d * DD;
    float aq = 0.f, ak = 0.f;
#pragma unroll
    for (int k = 0; k < DD; ++k) {
        float e = er[k];
        aq += e * wq[k];
        ak += e * wk[k];
    }
    eq[t] = aq;
    ek[t] = ak;
}

// ---------------- Kernel 2: per-edge score -> exp(score), atomic sum into dst
// (segment_max skipped: |score| <= ||v||_1 ~ 6.4, exp cannot overflow fp32;
//  epsilon-term difference vs reference is <= ~7e-6 relative.)
__global__ void score_kernel(const float* __restrict__ eq,
                             const float* __restrict__ ek,
                             const int* __restrict__ src,
                             const int* __restrict__ dst,
                             const float* __restrict__ v,
                             float* __restrict__ exp_s,
                             float* __restrict__ sumexp) {
    int wave = (blockIdx.x * blockDim.x + threadIdx.x) >> 6;
    int lane = threadIdx.x & 63;
    if (wave >= N_EDGES) return;
    int s = src[wave], dn = dst[wave];
    float a = eq[(size_t)s * DD + lane] + ek[(size_t)dn * DD + lane];
    float p = tanhf(a) * v[lane];
#pragma unroll
    for (int off = 32; off; off >>= 1) p += __shfl_xor(p, off);
    if (lane == 0) {
        float es = expf(p);
        exp_s[wave] = es;
        atomicAdd(&sumexp[dn], es);
    }
}

// ---------------- Kernel 3: weighted scatter-add aggregation (fp32 atomics)
__global__ void agg_kernel(const float* __restrict__ x,
                           const int* __restrict__ src,
                           const int* __restrict__ dst,
                           const float* __restrict__ exp_s,
                           const float* __restrict__ sumexp,
                           float* __restrict__ agg) {
    int wave = (blockIdx.x * blockDim.x + threadIdx.x) >> 6;
    int lane = threadIdx.x & 63;
    if (wave >= N_EDGES) return;
    int s = src[wave], dn = dst[wave];
    float w = exp_s[wave] / (sumexp[dn] + 1e-8f);
    const float* xs0 = x + (size_t)s * WFEAT;                      // batch 0
    const float* xs1 = x + (size_t)(N_NODES + s) * WFEAT;          // batch 1
    float* a0 = agg + (size_t)dn * WFEAT;
    float* a1 = agg + (size_t)(N_NODES + dn) * WFEAT;
    atomicAdd(&a0[lane],      w * xs0[lane]);
    atomicAdd(&a0[lane + 64], w * xs0[lane + 64]);
    atomicAdd(&a1[lane],      w * xs1[lane]);
    atomicAdd(&a1[lane + 64], w * xs1[lane + 64]);
}

// ---------------- Kernel 4: out = relu([x, agg] @ fcW^T + fcb)
// fcW^T staged in LDS (transposed layout avoids 32-way bank conflicts);
// each wave processes 4 rows at a time to amortize weight reads.
#define FC_R 4
__global__ __launch_bounds__(256, 1) void fc_kernel(const float* __restrict__ x,
                                                    const float* __restrict__ agg,
                                                    const float* __restrict__ fcW,
                                                    const float* __restrict__ fcb,
                                                    float* __restrict__ out) {
    __shared__ float wT[256 * 128];          // wT[i*128 + o] = fcW[o*256 + i]  (128 KB)
    __shared__ float rbuf[4][256][FC_R];     // [wave][i][r]                    (16 KB)
    int tid = threadIdx.x;
    for (int idx = tid; idx < 128 * 256; idx += 256) {
        int o = idx >> 8, i = idx & 255;
        wT[i * 128 + o] = fcW[idx];
    }
    __syncthreads();

    int wave = tid >> 6, lane = tid & 63;
    int gwave = blockIdx.x * 4 + wave;
    int nwaves = gridDim.x * 4;
    const int ROWS = BB * N_NODES;           // 100000
    float b0 = fcb[lane], b1 = fcb[lane + 64];

    for (int row0 = gwave * FC_R; row0 < ROWS; row0 += nwaves * FC_R) {
        int nr = min(FC_R, ROWS - row0);
        for (int r = 0; r < nr; ++r) {
            int row = row0 + r;
            const float* xr = x + (size_t)row * WFEAT;
            const float* ar = agg + (size_t)row * WFEAT;
            for (int j = lane; j < WFEAT; j += 64) {
                rbuf[wave][j][r]       = xr[j];
                rbuf[wave][128 + j][r] = ar[j];
            }
        }
        float acc0[FC_R], acc1[FC_R];
#pragma unroll
        for (int r = 0; r < FC_R; ++r) { acc0[r] = b0; acc1[r] = b1; }
#pragma unroll 4
        for (int i = 0; i < 256; ++i) {
            float w0 = wT[i * 128 + lane];
            float w1 = wT[i * 128 + 64 + lane];
            float4 rv = *reinterpret_cast<const float4*>(&rbuf[wave][i][0]);
            acc0[0] += rv.x * w0;  acc1[0] += rv.x * w1;
            acc0[1] += rv.y * w0;  acc1[1] += rv.y * w1;
            acc0[2] += rv.z * w0;  acc1[2] += rv.z * w1;
            acc0[3] += rv.w * w0;  acc1[3] += rv.w * w1;
        }
        for (int r = 0; r < nr; ++r) {
            int row = row0 + r;
            float* orow = out + (size_t)row * OUTD;
            orow[lane]      = fmaxf(acc0[r], 0.f);
            orow[lane + 64] = fmaxf(acc1[r], 0.f);
        }
    }
}

extern "C" void kernel_launch(void* const* d_in, const int* in_sizes, int n_in,
                              void* d_out, int out_size, void* d_ws, size_t ws_size,
                              hipStream_t stream) {
    const float* x    = (const float*)d_in[0];
    const float* emb  = (const float*)d_in[1];
    const int*   eidx = (const int*)d_in[2];
    const float* Wq   = (const float*)d_in[3];
    const float* Wk   = (const float*)d_in[4];
    const float* v    = (const float*)d_in[5];
    const float* fcW  = (const float*)d_in[6];
    const float* fcb  = (const float*)d_in[7];
    float* out = (float*)d_out;

    float* ws = (float*)d_ws;
    float* eq     = ws;                          // N*64
    float* ek     = eq + (size_t)N_NODES * DD;   // N*64
    float* exps   = ek + (size_t)N_NODES * DD;   // E
    float* sumexp = exps + N_EDGES;              // N
    float* agg    = sumexp + N_NODES;            // B*N*128

    const int* srcp = eidx;
    const int* dstp = eidx + N_EDGES;

    hipMemsetAsync(sumexp, 0, (size_t)N_NODES * sizeof(float), stream);
    hipMemsetAsync(agg, 0, (size_t)BB * N_NODES * WFEAT * sizeof(float), stream);

    proj_kernel<<<(N_NODES * DD + 255) / 256, 256, 0, stream>>>(emb, Wq, Wk, eq, ek);
    score_kernel<<<(N_EDGES + 3) / 4, 256, 0, stream>>>(eq, ek, srcp, dstp, v, exps, sumexp);
    agg_kernel<<<(N_EDGES + 3) / 4, 256, 0, stream>>>(x, srcp, dstp, exps, sumexp, agg);
    fc_kernel<<<512, 256, 0, stream>>>(x, agg, fcW, fcb, out);
}

// Round 2
// 839.676 us; speedup vs baseline: 1.5350x; 1.5350x over previous
//
#include <hip/hip_runtime.h>
#include <hip/hip_bf16.h>
#include <math.h>

#define N_NODES 50000
#define N_EDGES 800000
#define BB 2
#define WFEAT 128
#define DD 64
#define OUTD 128
#define SCAN_B 256
#define NBLK ((N_NODES + SCAN_B - 1) / SCAN_B)   // 196

// ---------------- Kernel 1: node projections e_q = emb @ Wq^T, e_k = emb @ Wk^T
__global__ void proj_kernel(const float* __restrict__ emb,
                            const float* __restrict__ Wq,
                            const float* __restrict__ Wk,
                            float* __restrict__ eq, float* __restrict__ ek) {
    int t = blockIdx.x * blockDim.x + threadIdx.x;   // over N*D
    if (t >= N_NODES * DD) return;
    int n = t >> 6, d = t & 63;
    const float* er = emb + (size_t)n * DD;
    const float* wq = Wq + (size_t)d * DD;
    const float* wk = Wk + (size_t)d * DD;
    float aq = 0.f, ak = 0.f;
#pragma unroll
    for (int k = 0; k < DD; ++k) {
        float e = er[k];
        aq += e * wq[k];
        ak += e * wk[k];
    }
    eq[t] = aq;
    ek[t] = ak;
}

// ---------------- Kernel 2: per-edge score -> exp(score)
// (segment_max skipped: |score| <= ||v||_1 ~ 6.4, exp cannot overflow fp32.)
__global__ void score_kernel(const float* __restrict__ eq,
                             const float* __restrict__ ek,
                             const int* __restrict__ src,
                             const int* __restrict__ dst,
                             const float* __restrict__ v,
                             float* __restrict__ exp_s) {
    int wave = (blockIdx.x * blockDim.x + threadIdx.x) >> 6;
    int lane = threadIdx.x & 63;
    if (wave >= N_EDGES) return;
    int s = src[wave], dn = dst[wave];
    float a = eq[(size_t)s * DD + lane] + ek[(size_t)dn * DD + lane];
    float p = tanhf(a) * v[lane];
#pragma unroll
    for (int off = 32; off; off >>= 1) p += __shfl_xor(p, off);
    if (lane == 0) exp_s[wave] = expf(p);
}

// ---------------- CSR build: histogram -> scan -> scatter
__global__ void hist_kernel(const int* __restrict__ dst, int* __restrict__ deg) {
    int e = blockIdx.x * blockDim.x + threadIdx.x;
    if (e < N_EDGES) atomicAdd(&deg[dst[e]], 1);
}

__global__ void scan_reduce(const int* __restrict__ deg, int* __restrict__ bsum) {
    __shared__ int sh[SCAN_B];
    int i = blockIdx.x * SCAN_B + threadIdx.x;
    sh[threadIdx.x] = (i < N_NODES) ? deg[i] : 0;
    __syncthreads();
    for (int s = SCAN_B / 2; s; s >>= 1) {
        if (threadIdx.x < s) sh[threadIdx.x] += sh[threadIdx.x + s];
        __syncthreads();
    }
    if (threadIdx.x == 0) bsum[blockIdx.x] = sh[0];
}

__global__ void scan_bsum(int* __restrict__ bsum) {
    if (threadIdx.x == 0 && blockIdx.x == 0) {
        int acc = 0;
        for (int i = 0; i < NBLK; ++i) { int t = bsum[i]; bsum[i] = acc; acc += t; }
    }
}

__global__ void scan_final(const int* __restrict__ deg, const int* __restrict__ bsum,
                           int* __restrict__ rowptr, int* __restrict__ cursor) {
    __shared__ int sh[SCAN_B];
    int i = blockIdx.x * SCAN_B + threadIdx.x;
    int v = (i < N_NODES) ? deg[i] : 0;
    sh[threadIdx.x] = v;
    __syncthreads();
    for (int s = 1; s < SCAN_B; s <<= 1) {
        int t = 0;
        if ((int)threadIdx.x >= s) t = sh[threadIdx.x - s];
        __syncthreads();
        sh[threadIdx.x] += t;
        __syncthreads();
    }
    if (i < N_NODES) {
        int excl = sh[threadIdx.x] - v + bsum[blockIdx.x];
        rowptr[i] = excl;
        cursor[i] = excl;
        if (i == N_NODES - 1) rowptr[N_NODES] = excl + v;
    }
}

__global__ void scatter_kernel(const int* __restrict__ src, const int* __restrict__ dst,
                               const float* __restrict__ exp_s,
                               int* __restrict__ cursor,
                               int* __restrict__ src_sorted, float* __restrict__ exps_sorted) {
    int e = blockIdx.x * blockDim.x + threadIdx.x;
    if (e >= N_EDGES) return;
    int d = dst[e];
    int pos = atomicAdd(&cursor[d], 1);
    src_sorted[pos] = src[e];
    exps_sorted[pos] = exp_s[e];
}

// ---------------- Kernel 3: CSR aggregation — one wave per dst node, register acc
__global__ void agg_csr_kernel(const float* __restrict__ x,
                               const int* __restrict__ rowptr,
                               const int* __restrict__ src_sorted,
                               const float* __restrict__ exps_sorted,
                               float* __restrict__ agg) {
    int node = (blockIdx.x * blockDim.x + threadIdx.x) >> 6;
    int lane = threadIdx.x & 63;
    if (node >= N_NODES) return;
    int p = rowptr[node], end = rowptr[node + 1];
    const float2* x0 = (const float2*)x;                                 // batch 0
    const float2* x1 = (const float2*)(x + (size_t)N_NODES * WFEAT);     // batch 1
    float a0x = 0.f, a0y = 0.f, a1x = 0.f, a1y = 0.f, sum = 0.f;
#pragma unroll 2
    for (; p < end; ++p) {
        int s = src_sorted[p];
        float es = exps_sorted[p];
        sum += es;
        float2 v0 = x0[(size_t)s * 64 + lane];
        float2 v1 = x1[(size_t)s * 64 + lane];
        a0x += es * v0.x; a0y += es * v0.y;
        a1x += es * v1.x; a1y += es * v1.y;
    }
    float inv = 1.f / (sum + 1e-8f);
    float2* o0 = (float2*)(agg + (size_t)node * WFEAT);
    float2* o1 = (float2*)(agg + (size_t)(N_NODES + node) * WFEAT);
    o0[lane] = make_float2(a0x * inv, a0y * inv);
    o1[lane] = make_float2(a1x * inv, a1y * inv);
}

// ---------------- Kernel 4: out = relu([x, agg] @ fcW^T + fcb)
#define FC_R 4
__global__ __launch_bounds__(256, 1) void fc_kernel(const float* __restrict__ x,
                                                    const float* __restrict__ agg,
                                                    const float* __restrict__ fcW,
                                                    const float* __restrict__ fcb,
                                                    float* __restrict__ out) {
    __shared__ float wT[256 * 128];          // wT[i*128 + o] = fcW[o*256 + i]  (128 KB)
    __shared__ float rbuf[4][256][FC_R];     // [wave][i][r]                    (16 KB)
    int tid = threadIdx.x;
    for (int idx = tid; idx < 128 * 256; idx += 256) {
        int o = idx >> 8, i = idx & 255;
        wT[i * 128 + o] = fcW[idx];
    }
    __syncthreads();

    int wave = tid >> 6, lane = tid & 63;
    int gwave = blockIdx.x * 4 + wave;
    int nwaves = gridDim.x * 4;
    const int ROWS = BB * N_NODES;           // 100000
    float b0 = fcb[lane], b1 = fcb[lane + 64];

    for (int row0 = gwave * FC_R; row0 < ROWS; row0 += nwaves * FC_R) {
        int nr = min(FC_R, ROWS - row0);
        for (int r = 0; r < nr; ++r) {
            int row = row0 + r;
            const float* xr = x + (size_t)row * WFEAT;
            const float* ar = agg + (size_t)row * WFEAT;
            for (int j = lane; j < WFEAT; j += 64) {
                rbuf[wave][j][r]       = xr[j];
                rbuf[wave][128 + j][r] = ar[j];
            }
        }
        float acc0[FC_R], acc1[FC_R];
#pragma unroll
        for (int r = 0; r < FC_R; ++r) { acc0[r] = b0; acc1[r] = b1; }
#pragma unroll 4
        for (int i = 0; i < 256; ++i) {
            float w0 = wT[i * 128 + lane];
            float w1 = wT[i * 128 + 64 + lane];
            float4 rv = *reinterpret_cast<const float4*>(&rbuf[wave][i][0]);
            acc0[0] += rv.x * w0;  acc1[0] += rv.x * w1;
            acc0[1] += rv.y * w0;  acc1[1] += rv.y * w1;
            acc0[2] += rv.z * w0;  acc1[2] += rv.z * w1;
            acc0[3] += rv.w * w0;  acc1[3] += rv.w * w1;
        }
        for (int r = 0; r < nr; ++r) {
            int row = row0 + r;
            float* orow = out + (size_t)row * OUTD;
            orow[lane]      = fmaxf(acc0[r], 0.f);
            orow[lane + 64] = fmaxf(acc1[r], 0.f);
        }
    }
}

extern "C" void kernel_launch(void* const* d_in, const int* in_sizes, int n_in,
                              void* d_out, int out_size, void* d_ws, size_t ws_size,
                              hipStream_t stream) {
    const float* x    = (const float*)d_in[0];
    const float* emb  = (const float*)d_in[1];
    const int*   eidx = (const int*)d_in[2];
    const float* Wq   = (const float*)d_in[3];
    const float* Wk   = (const float*)d_in[4];
    const float* v    = (const float*)d_in[5];
    const float* fcW  = (const float*)d_in[6];
    const float* fcb  = (const float*)d_in[7];
    float* out = (float*)d_out;

    float* ws = (float*)d_ws;
    float* eq          = ws;                                   // N*64
    float* ek          = eq + (size_t)N_NODES * DD;            // N*64
    float* exps        = ek + (size_t)N_NODES * DD;            // E
    float* exps_sorted = exps + N_EDGES;                       // E
    float* agg         = exps_sorted + N_EDGES;                // B*N*128
    int*   deg         = (int*)(agg + (size_t)BB * N_NODES * WFEAT); // N
    int*   rowptr      = deg + N_NODES;                        // N+1
    int*   cursor      = rowptr + N_NODES + 1;                 // N
    int*   bsum        = cursor + N_NODES;                     // NBLK (pad 256)
    int*   src_sorted  = bsum + 256;                           // E

    const int* srcp = eidx;
    const int* dstp = eidx + N_EDGES;

    hipMemsetAsync(deg, 0, (size_t)N_NODES * sizeof(int), stream);

    proj_kernel<<<(N_NODES * DD + 255) / 256, 256, 0, stream>>>(emb, Wq, Wk, eq, ek);
    score_kernel<<<(N_EDGES + 3) / 4, 256, 0, stream>>>(eq, ek, srcp, dstp, v, exps);
    hist_kernel<<<(N_EDGES + 255) / 256, 256, 0, stream>>>(dstp, deg);
    scan_reduce<<<NBLK, SCAN_B, 0, stream>>>(deg, bsum);
    scan_bsum<<<1, 64, 0, stream>>>(bsum);
    scan_final<<<NBLK, SCAN_B, 0, stream>>>(deg, bsum, rowptr, cursor);
    scatter_kernel<<<(N_EDGES + 255) / 256, 256, 0, stream>>>(srcp, dstp, exps, cursor,
                                                              src_sorted, exps_sorted);
    agg_csr_kernel<<<(N_NODES * 64 + 255) / 256, 256, 0, stream>>>(x, rowptr, src_sorted,
                                                                   exps_sorted, agg);
    fc_kernel<<<512, 256, 0, stream>>>(x, agg, fcW, fcb, out);
}

// Round 3
// 578.229 us; speedup vs baseline: 2.2290x; 1.4522x over previous
//
#include <hip/hip_runtime.h>
#include <hip/hip_bf16.h>
#include <math.h>

#define N_NODES 50000
#define N_EDGES 800000
#define BB 2
#define WFEAT 128
#define DD 64
#define OUTD 128
#define NROWS (BB * N_NODES)      // 100000
#define SCAN_B 256
#define NBLK ((N_NODES + SCAN_B - 1) / SCAN_B)   // 196

typedef __attribute__((ext_vector_type(8))) short bf16x8;
typedef __attribute__((ext_vector_type(4))) float f32x4;
typedef __attribute__((ext_vector_type(8))) unsigned short ushort8;

static __device__ __forceinline__ unsigned short f2bf(float f) {
    __hip_bfloat16 h = __float2bfloat16(f);
    return *reinterpret_cast<unsigned short*>(&h);
}
static __device__ __forceinline__ float bf2f(unsigned short u) {
    unsigned int t = (unsigned int)u << 16;
    return *reinterpret_cast<float*>(&t);
}

// ---------------- convert fp32 -> bf16, 8 elems/thread
__global__ void cvt_bf16_kernel(const float* __restrict__ in, unsigned short* __restrict__ out,
                                int n8) {
    int t = blockIdx.x * blockDim.x + threadIdx.x;
    if (t >= n8) return;
    const float4* in4 = (const float4*)in;
    float4 a = in4[2 * t], b = in4[2 * t + 1];
    ushort8 o;
    o[0] = f2bf(a.x); o[1] = f2bf(a.y); o[2] = f2bf(a.z); o[3] = f2bf(a.w);
    o[4] = f2bf(b.x); o[5] = f2bf(b.y); o[6] = f2bf(b.z); o[7] = f2bf(b.w);
    *reinterpret_cast<ushort8*>(&out[8 * t]) = o;
}

// ---------------- Kernel 1: node projections e_q = emb @ Wq^T, e_k = emb @ Wk^T
__global__ void proj_kernel(const float* __restrict__ emb,
                            const float* __restrict__ Wq,
                            const float* __restrict__ Wk,
                            float* __restrict__ eq, float* __restrict__ ek) {
    int t = blockIdx.x * blockDim.x + threadIdx.x;   // over N*D
    if (t >= N_NODES * DD) return;
    int n = t >> 6, d = t & 63;
    const float* er = emb + (size_t)n * DD;
    const float* wq = Wq + (size_t)d * DD;
    const float* wk = Wk + (size_t)d * DD;
    float aq = 0.f, ak = 0.f;
#pragma unroll
    for (int k = 0; k < DD; ++k) {
        float e = er[k];
        aq += e * wq[k];
        ak += e * wk[k];
    }
    eq[t] = aq;
    ek[t] = ak;
}

// ---------------- Kernel 2: per-edge score -> exp(score)
// (segment_max skipped: |score| <= ||v||_1 ~ 6.4, exp cannot overflow fp32.)
__global__ void score_kernel(const float* __restrict__ eq,
                             const float* __restrict__ ek,
                             const int* __restrict__ src,
                             const int* __restrict__ dst,
                             const float* __restrict__ v,
                             float* __restrict__ exp_s) {
    int wave = (blockIdx.x * blockDim.x + threadIdx.x) >> 6;
    int lane = threadIdx.x & 63;
    if (wave >= N_EDGES) return;
    int s = src[wave], dn = dst[wave];
    float a = eq[(size_t)s * DD + lane] + ek[(size_t)dn * DD + lane];
    float p = tanhf(a) * v[lane];
#pragma unroll
    for (int off = 32; off; off >>= 1) p += __shfl_xor(p, off);
    if (lane == 0) exp_s[wave] = expf(p);
}

// ---------------- CSR build: histogram -> scan -> scatter
__global__ void hist_kernel(const int* __restrict__ dst, int* __restrict__ deg) {
    int e = blockIdx.x * blockDim.x + threadIdx.x;
    if (e < N_EDGES) atomicAdd(&deg[dst[e]], 1);
}

__global__ void scan_reduce(const int* __restrict__ deg, int* __restrict__ bsum) {
    __shared__ int sh[SCAN_B];
    int i = blockIdx.x * SCAN_B + threadIdx.x;
    sh[threadIdx.x] = (i < N_NODES) ? deg[i] : 0;
    __syncthreads();
    for (int s = SCAN_B / 2; s; s >>= 1) {
        if (threadIdx.x < s) sh[threadIdx.x] += sh[threadIdx.x + s];
        __syncthreads();
    }
    if (threadIdx.x == 0) bsum[blockIdx.x] = sh[0];
}

__global__ void scan_bsum(int* __restrict__ bsum) {
    if (threadIdx.x == 0 && blockIdx.x == 0) {
        int acc = 0;
        for (int i = 0; i < NBLK; ++i) { int t = bsum[i]; bsum[i] = acc; acc += t; }
    }
}

__global__ void scan_final(const int* __restrict__ deg, const int* __restrict__ bsum,
                           int* __restrict__ rowptr, int* __restrict__ cursor) {
    __shared__ int sh[SCAN_B];
    int i = blockIdx.x * SCAN_B + threadIdx.x;
    int v = (i < N_NODES) ? deg[i] : 0;
    sh[threadIdx.x] = v;
    __syncthreads();
    for (int s = 1; s < SCAN_B; s <<= 1) {
        int t = 0;
        if ((int)threadIdx.x >= s) t = sh[threadIdx.x - s];
        __syncthreads();
        sh[threadIdx.x] += t;
        __syncthreads();
    }
    if (i < N_NODES) {
        int excl = sh[threadIdx.x] - v + bsum[blockIdx.x];
        rowptr[i] = excl;
        cursor[i] = excl;
        if (i == N_NODES - 1) rowptr[N_NODES] = excl + v;
    }
}

__global__ void scatter_kernel(const int* __restrict__ src, const int* __restrict__ dst,
                               const float* __restrict__ exp_s,
                               int* __restrict__ cursor,
                               int* __restrict__ src_sorted, float* __restrict__ exps_sorted) {
    int e = blockIdx.x * blockDim.x + threadIdx.x;
    if (e >= N_EDGES) return;
    int d = dst[e];
    int pos = atomicAdd(&cursor[d], 1);
    src_sorted[pos] = src[e];
    exps_sorted[pos] = exp_s[e];
}

// ---------------- Kernel 3: CSR aggregation — one wave per dst node, bf16 gathers
__global__ void agg_csr_kernel(const unsigned short* __restrict__ xb,
                               const int* __restrict__ rowptr,
                               const int* __restrict__ src_sorted,
                               const float* __restrict__ exps_sorted,
                               unsigned short* __restrict__ aggb) {
    int node = (blockIdx.x * blockDim.x + threadIdx.x) >> 6;
    int lane = threadIdx.x & 63;
    if (node >= N_NODES) return;
    int p = rowptr[node], end = rowptr[node + 1];
    const unsigned short* x0 = xb;                                // batch 0
    const unsigned short* x1 = xb + (size_t)N_NODES * WFEAT;      // batch 1
    float a0x = 0.f, a0y = 0.f, a1x = 0.f, a1y = 0.f, sum = 0.f;
#pragma unroll 2
    for (; p < end; ++p) {
        int s = src_sorted[p];
        float es = exps_sorted[p];
        sum += es;
        unsigned int u0 = *reinterpret_cast<const unsigned int*>(&x0[(size_t)s * WFEAT + lane * 2]);
        unsigned int u1 = *reinterpret_cast<const unsigned int*>(&x1[(size_t)s * WFEAT + lane * 2]);
        a0x += es * bf2f((unsigned short)u0);
        a0y += es * bf2f((unsigned short)(u0 >> 16));
        a1x += es * bf2f((unsigned short)u1);
        a1y += es * bf2f((unsigned short)(u1 >> 16));
    }
    float inv = 1.f / (sum + 1e-8f);
    unsigned int o0 = (unsigned int)f2bf(a0x * inv) | ((unsigned int)f2bf(a0y * inv) << 16);
    unsigned int o1 = (unsigned int)f2bf(a1x * inv) | ((unsigned int)f2bf(a1y * inv) << 16);
    *reinterpret_cast<unsigned int*>(&aggb[(size_t)node * WFEAT + lane * 2]) = o0;
    *reinterpret_cast<unsigned int*>(&aggb[(size_t)(N_NODES + node) * WFEAT + lane * 2]) = o1;
}

// ---------------- Kernel 4: out = relu([x, agg] @ fcW^T + fcb) via bf16 MFMA
// A = [100000 x 256] (concat xb|aggb), B^T = fcWb row-major [128 n][256 k].
// BM=128, BN=128, BK=64; 4 waves (2x2), each wave 64x64 = 4x4 16x16 frags.
// LDS tiles [row][k] with byte ^= (row&7)<<4 swizzle (kills stride-128B conflicts).
__global__ __launch_bounds__(256) void fc_mfma(const unsigned short* __restrict__ xb,
                                               const unsigned short* __restrict__ aggb,
                                               const unsigned short* __restrict__ fcWb,
                                               const float* __restrict__ fcb,
                                               float* __restrict__ out) {
    __shared__ unsigned short As[128 * 64];   // 16 KB, swizzled [r][k]
    __shared__ unsigned short Bs[128 * 64];   // 16 KB, swizzled [n][k]
    int tid = threadIdx.x;
    int wave = tid >> 6, lane = tid & 63;
    int wm = wave >> 1, wn = wave & 1;
    int row0 = blockIdx.x * 128;

    f32x4 acc[4][4] = {};

    for (int ks = 0; ks < 4; ++ks) {
        const unsigned short* Asrc = (ks < 2) ? xb : aggb;
        int kbase = (ks & 1) * 64;
        __syncthreads();
#pragma unroll
        for (int c = 0; c < 4; ++c) {
            int idx = (c * 256 + tid) * 8;       // element idx in 128x64 tile
            int r = idx >> 6, k = idx & 63;
            int row = row0 + r;
            ulonglong2 val = make_ulonglong2(0ull, 0ull);
            if (row < NROWS)
                val = *reinterpret_cast<const ulonglong2*>(&Asrc[(size_t)row * WFEAT + kbase + k]);
            int byte = (r * 128 + k * 2) ^ ((r & 7) << 4);
            *reinterpret_cast<ulonglong2*>(reinterpret_cast<char*>(As) + byte) = val;

            ulonglong2 wv = *reinterpret_cast<const ulonglong2*>(&fcWb[(size_t)r * 256 + ks * 64 + k]);
            *reinterpret_cast<ulonglong2*>(reinterpret_cast<char*>(Bs) + byte) = wv;
        }
        __syncthreads();
#pragma unroll
        for (int kk = 0; kk < 2; ++kk) {
            bf16x8 a[4], b[4];
#pragma unroll
            for (int m = 0; m < 4; ++m) {
                int r = wm * 64 + m * 16 + (lane & 15);
                int k = kk * 32 + (lane >> 4) * 8;
                int byte = (r * 128 + k * 2) ^ ((r & 7) << 4);
                a[m] = *reinterpret_cast<bf16x8*>(reinterpret_cast<char*>(As) + byte);
            }
#pragma unroll
            for (int n = 0; n < 4; ++n) {
                int cn = wn * 64 + n * 16 + (lane & 15);
                int k = kk * 32 + (lane >> 4) * 8;
                int byte = (cn * 128 + k * 2) ^ ((cn & 7) << 4);
                b[n] = *reinterpret_cast<bf16x8*>(reinterpret_cast<char*>(Bs) + byte);
            }
#pragma unroll
            for (int m = 0; m < 4; ++m)
#pragma unroll
                for (int n = 0; n < 4; ++n)
                    acc[m][n] = __builtin_amdgcn_mfma_f32_16x16x32_bf16(a[m], b[n], acc[m][n], 0, 0, 0);
        }
    }
    // C/D layout: col = lane&15, row = (lane>>4)*4 + j
#pragma unroll
    for (int m = 0; m < 4; ++m) {
#pragma unroll
        for (int n = 0; n < 4; ++n) {
            int col = wn * 64 + n * 16 + (lane & 15);
            float bias = fcb[col];
#pragma unroll
            for (int j = 0; j < 4; ++j) {
                int row = row0 + wm * 64 + m * 16 + (lane >> 4) * 4 + j;
                if (row < NROWS)
                    out[(size_t)row * OUTD + col] = fmaxf(acc[m][n][j] + bias, 0.f);
            }
        }
    }
}

extern "C" void kernel_launch(void* const* d_in, const int* in_sizes, int n_in,
                              void* d_out, int out_size, void* d_ws, size_t ws_size,
                              hipStream_t stream) {
    const float* x    = (const float*)d_in[0];
    const float* emb  = (const float*)d_in[1];
    const int*   eidx = (const int*)d_in[2];
    const float* Wq   = (const float*)d_in[3];
    const float* Wk   = (const float*)d_in[4];
    const float* v    = (const float*)d_in[5];
    const float* fcW  = (const float*)d_in[6];
    const float* fcb  = (const float*)d_in[7];
    float* out = (float*)d_out;

    char* ws = (char*)d_ws;
    float* eq          = (float*)ws;                             ws += (size_t)N_NODES * DD * 4;
    float* ek          = (float*)ws;                             ws += (size_t)N_NODES * DD * 4;
    float* exps        = (float*)ws;                             ws += (size_t)N_EDGES * 4;
    float* exps_sorted = (float*)ws;                             ws += (size_t)N_EDGES * 4;
    unsigned short* xb   = (unsigned short*)ws;                  ws += (size_t)NROWS * WFEAT * 2;
    unsigned short* aggb = (unsigned short*)ws;                  ws += (size_t)NROWS * WFEAT * 2;
    unsigned short* fcWb = (unsigned short*)ws;                  ws += (size_t)OUTD * 256 * 2;
    int* deg        = (int*)ws;                                  ws += (size_t)N_NODES * 4;
    int* rowptr     = (int*)ws;                                  ws += (size_t)(N_NODES + 1) * 4 + 12;
    int* cursor     = (int*)ws;                                  ws += (size_t)N_NODES * 4;
    int* bsum       = (int*)ws;                                  ws += 256 * 4;
    int* src_sorted = (int*)ws;

    const int* srcp = eidx;
    const int* dstp = eidx + N_EDGES;

    hipMemsetAsync(deg, 0, (size_t)N_NODES * sizeof(int), stream);

    cvt_bf16_kernel<<<(NROWS * WFEAT / 8 + 255) / 256, 256, 0, stream>>>(x, xb, NROWS * WFEAT / 8);
    cvt_bf16_kernel<<<(OUTD * 256 / 8 + 255) / 256, 256, 0, stream>>>(fcW, fcWb, OUTD * 256 / 8);
    proj_kernel<<<(N_NODES * DD + 255) / 256, 256, 0, stream>>>(emb, Wq, Wk, eq, ek);
    score_kernel<<<(N_EDGES + 3) / 4, 256, 0, stream>>>(eq, ek, srcp, dstp, v, exps);
    hist_kernel<<<(N_EDGES + 255) / 256, 256, 0, stream>>>(dstp, deg);
    scan_reduce<<<NBLK, SCAN_B, 0, stream>>>(deg, bsum);
    scan_bsum<<<1, 64, 0, stream>>>(bsum);
    scan_final<<<NBLK, SCAN_B, 0, stream>>>(deg, bsum, rowptr, cursor);
    scatter_kernel<<<(N_EDGES + 255) / 256, 256, 0, stream>>>(srcp, dstp, exps, cursor,
                                                              src_sorted, exps_sorted);
    agg_csr_kernel<<<(N_NODES * 64 + 255) / 256, 256, 0, stream>>>(xb, rowptr, src_sorted,
                                                                   exps_sorted, aggb);
    fc_mfma<<<(NROWS + 127) / 128, 256, 0, stream>>>(xb, aggb, fcWb, fcb, out);
}

// Round 4
// 417.783 us; speedup vs baseline: 3.0851x; 1.3840x over previous
//
#include <hip/hip_runtime.h>
#include <hip/hip_bf16.h>
#include <math.h>

#define N_NODES 50000
#define N_EDGES 800000
#define BB 2
#define WFEAT 128
#define DD 64
#define OUTD 128
#define NROWS (BB * N_NODES)      // 100000
#define SCAN_B 256
#define NBLK ((N_NODES + SCAN_B - 1) / SCAN_B)   // 196

typedef __attribute__((ext_vector_type(8))) short bf16x8;
typedef __attribute__((ext_vector_type(4))) float f32x4;
typedef __attribute__((ext_vector_type(8))) unsigned short ushort8;

static __device__ __forceinline__ unsigned short f2bf(float f) {
    __hip_bfloat16 h = __float2bfloat16(f);
    return *reinterpret_cast<unsigned short*>(&h);
}
static __device__ __forceinline__ float bf2f(unsigned short u) {
    unsigned int t = (unsigned int)u << 16;
    return *reinterpret_cast<float*>(&t);
}

// ---------------- convert fp32 -> bf16, 8 elems/thread
__global__ void cvt_bf16_kernel(const float* __restrict__ in, unsigned short* __restrict__ out,
                                int n8) {
    int t = blockIdx.x * blockDim.x + threadIdx.x;
    if (t >= n8) return;
    const float4* in4 = (const float4*)in;
    float4 a = in4[2 * t], b = in4[2 * t + 1];
    ushort8 o;
    o[0] = f2bf(a.x); o[1] = f2bf(a.y); o[2] = f2bf(a.z); o[3] = f2bf(a.w);
    o[4] = f2bf(b.x); o[5] = f2bf(b.y); o[6] = f2bf(b.z); o[7] = f2bf(b.w);
    *reinterpret_cast<ushort8*>(&out[8 * t]) = o;
}

// ---------------- Kernel 1: node projections e_q = emb @ Wq^T, e_k = emb @ Wk^T
// Weights staged transposed in LDS (stride 65 breaks bank aliasing); emb row
// comes in as wave-uniform float4 broadcasts. One wave per node.
__global__ __launch_bounds__(256) void proj_kernel(const float* __restrict__ emb,
                                                   const float* __restrict__ Wq,
                                                   const float* __restrict__ Wk,
                                                   float* __restrict__ eq,
                                                   float* __restrict__ ek) {
    __shared__ float wqT[64 * 65];   // wqT[k*65+d] = Wq[d*64+k]
    __shared__ float wkT[64 * 65];
    int tid = threadIdx.x;
    for (int idx = tid; idx < 4096; idx += 256) {
        int d = idx >> 6, k = idx & 63;
        wqT[k * 65 + d] = Wq[idx];
        wkT[k * 65 + d] = Wk[idx];
    }
    __syncthreads();

    int t = blockIdx.x * 256 + tid;          // grid covers N*64 exactly
    int n = t >> 6, d = t & 63;
    const float4* er4 = (const float4*)(emb + (size_t)n * DD);
    float aq = 0.f, ak = 0.f;
#pragma unroll
    for (int k4 = 0; k4 < 16; ++k4) {
        float4 e = er4[k4];
        int k = k4 * 4;
        aq += e.x * wqT[(k + 0) * 65 + d] + e.y * wqT[(k + 1) * 65 + d]
            + e.z * wqT[(k + 2) * 65 + d] + e.w * wqT[(k + 3) * 65 + d];
        ak += e.x * wkT[(k + 0) * 65 + d] + e.y * wkT[(k + 1) * 65 + d]
            + e.z * wkT[(k + 2) * 65 + d] + e.w * wkT[(k + 3) * 65 + d];
    }
    eq[t] = aq;
    ek[t] = ak;
}

// ---------------- Kernel 2: per-edge score -> exp(score)
// (segment_max skipped: |score| <= ||v||_1 ~ 6.4, exp cannot overflow fp32.)
__global__ void score_kernel(const float* __restrict__ eq,
                             const float* __restrict__ ek,
                             const int* __restrict__ src,
                             const int* __restrict__ dst,
                             const float* __restrict__ v,
                             float* __restrict__ exp_s) {
    int wave = (blockIdx.x * blockDim.x + threadIdx.x) >> 6;
    int lane = threadIdx.x & 63;
    if (wave >= N_EDGES) return;
    int s = src[wave], dn = dst[wave];
    float a = eq[(size_t)s * DD + lane] + ek[(size_t)dn * DD + lane];
    float p = tanhf(a) * v[lane];
#pragma unroll
    for (int off = 32; off; off >>= 1) p += __shfl_xor(p, off);
    if (lane == 0) exp_s[wave] = expf(p);
}

// ---------------- CSR build: histogram -> scan -> scatter
__global__ void hist_kernel(const int* __restrict__ dst, int* __restrict__ deg) {
    int e = blockIdx.x * blockDim.x + threadIdx.x;
    if (e < N_EDGES) atomicAdd(&deg[dst[e]], 1);
}

__global__ void scan_reduce(const int* __restrict__ deg, int* __restrict__ bsum) {
    __shared__ int sh[SCAN_B];
    int i = blockIdx.x * SCAN_B + threadIdx.x;
    sh[threadIdx.x] = (i < N_NODES) ? deg[i] : 0;
    __syncthreads();
    for (int s = SCAN_B / 2; s; s >>= 1) {
        if (threadIdx.x < s) sh[threadIdx.x] += sh[threadIdx.x + s];
        __syncthreads();
    }
    if (threadIdx.x == 0) bsum[blockIdx.x] = sh[0];
}

__global__ void scan_bsum(int* __restrict__ bsum) {
    if (threadIdx.x == 0 && blockIdx.x == 0) {
        int acc = 0;
        for (int i = 0; i < NBLK; ++i) { int t = bsum[i]; bsum[i] = acc; acc += t; }
    }
}

__global__ void scan_final(const int* __restrict__ deg, const int* __restrict__ bsum,
                           int* __restrict__ rowptr, int* __restrict__ cursor) {
    __shared__ int sh[SCAN_B];
    int i = blockIdx.x * SCAN_B + threadIdx.x;
    int v = (i < N_NODES) ? deg[i] : 0;
    sh[threadIdx.x] = v;
    __syncthreads();
    for (int s = 1; s < SCAN_B; s <<= 1) {
        int t = 0;
        if ((int)threadIdx.x >= s) t = sh[threadIdx.x - s];
        __syncthreads();
        sh[threadIdx.x] += t;
        __syncthreads();
    }
    if (i < N_NODES) {
        int excl = sh[threadIdx.x] - v + bsum[blockIdx.x];
        rowptr[i] = excl;
        cursor[i] = excl;
        if (i == N_NODES - 1) rowptr[N_NODES] = excl + v;
    }
}

__global__ void scatter_kernel(const int* __restrict__ src, const int* __restrict__ dst,
                               const float* __restrict__ exp_s,
                               int* __restrict__ cursor,
                               int* __restrict__ src_sorted, float* __restrict__ exps_sorted) {
    int e = blockIdx.x * blockDim.x + threadIdx.x;
    if (e >= N_EDGES) return;
    int d = dst[e];
    int pos = atomicAdd(&cursor[d], 1);
    src_sorted[pos] = src[e];
    exps_sorted[pos] = exp_s[e];
}

// ---------------- Kernel 3: CSR aggregation — one wave per dst node, bf16 gathers
__global__ void agg_csr_kernel(const unsigned short* __restrict__ xb,
                               const int* __restrict__ rowptr,
                               const int* __restrict__ src_sorted,
                               const float* __restrict__ exps_sorted,
                               unsigned short* __restrict__ aggb) {
    int node = (blockIdx.x * blockDim.x + threadIdx.x) >> 6;
    int lane = threadIdx.x & 63;
    if (node >= N_NODES) return;
    int p = rowptr[node], end = rowptr[node + 1];
    const unsigned short* x0 = xb;                                // batch 0
    const unsigned short* x1 = xb + (size_t)N_NODES * WFEAT;      // batch 1
    float a0x = 0.f, a0y = 0.f, a1x = 0.f, a1y = 0.f, sum = 0.f;
#pragma unroll 2
    for (; p < end; ++p) {
        int s = src_sorted[p];
        float es = exps_sorted[p];
        sum += es;
        unsigned int u0 = *reinterpret_cast<const unsigned int*>(&x0[(size_t)s * WFEAT + lane * 2]);
        unsigned int u1 = *reinterpret_cast<const unsigned int*>(&x1[(size_t)s * WFEAT + lane * 2]);
        a0x += es * bf2f((unsigned short)u0);
        a0y += es * bf2f((unsigned short)(u0 >> 16));
        a1x += es * bf2f((unsigned short)u1);
        a1y += es * bf2f((unsigned short)(u1 >> 16));
    }
    float inv = 1.f / (sum + 1e-8f);
    unsigned int o0 = (unsigned int)f2bf(a0x * inv) | ((unsigned int)f2bf(a0y * inv) << 16);
    unsigned int o1 = (unsigned int)f2bf(a1x * inv) | ((unsigned int)f2bf(a1y * inv) << 16);
    *reinterpret_cast<unsigned int*>(&aggb[(size_t)node * WFEAT + lane * 2]) = o0;
    *reinterpret_cast<unsigned int*>(&aggb[(size_t)(N_NODES + node) * WFEAT + lane * 2]) = o1;
}

// ---------------- Kernel 4: out = relu([x, agg] @ fcW^T + fcb) via bf16 MFMA
// A = [100000 x 256] (concat xb|aggb), B^T = fcWb row-major [128 n][256 k].
// BM=128, BN=128, BK=64; 4 waves (2x2), each wave 64x64 = 4x4 16x16 frags.
// LDS tiles [row][k] with byte ^= (row&7)<<4 swizzle (kills stride-128B conflicts).
__global__ __launch_bounds__(256) void fc_mfma(const unsigned short* __restrict__ xb,
                                               const unsigned short* __restrict__ aggb,
                                               const unsigned short* __restrict__ fcWb,
                                               const float* __restrict__ fcb,
                                               float* __restrict__ out) {
    __shared__ unsigned short As[128 * 64];   // 16 KB, swizzled [r][k]
    __shared__ unsigned short Bs[128 * 64];   // 16 KB, swizzled [n][k]
    int tid = threadIdx.x;
    int wave = tid >> 6, lane = tid & 63;
    int wm = wave >> 1, wn = wave & 1;
    int row0 = blockIdx.x * 128;

    f32x4 acc[4][4] = {};

    for (int ks = 0; ks < 4; ++ks) {
        const unsigned short* Asrc = (ks < 2) ? xb : aggb;
        int kbase = (ks & 1) * 64;
        __syncthreads();
#pragma unroll
        for (int c = 0; c < 4; ++c) {
            int idx = (c * 256 + tid) * 8;       // element idx in 128x64 tile
            int r = idx >> 6, k = idx & 63;
            int row = row0 + r;
            ulonglong2 val = make_ulonglong2(0ull, 0ull);
            if (row < NROWS)
                val = *reinterpret_cast<const ulonglong2*>(&Asrc[(size_t)row * WFEAT + kbase + k]);
            int byte = (r * 128 + k * 2) ^ ((r & 7) << 4);
            *reinterpret_cast<ulonglong2*>(reinterpret_cast<char*>(As) + byte) = val;

            ulonglong2 wv = *reinterpret_cast<const ulonglong2*>(&fcWb[(size_t)r * 256 + ks * 64 + k]);
            *reinterpret_cast<ulonglong2*>(reinterpret_cast<char*>(Bs) + byte) = wv;
        }
        __syncthreads();
#pragma unroll
        for (int kk = 0; kk < 2; ++kk) {
            bf16x8 a[4], b[4];
#pragma unroll
            for (int m = 0; m < 4; ++m) {
                int r = wm * 64 + m * 16 + (lane & 15);
                int k = kk * 32 + (lane >> 4) * 8;
                int byte = (r * 128 + k * 2) ^ ((r & 7) << 4);
                a[m] = *reinterpret_cast<bf16x8*>(reinterpret_cast<char*>(As) + byte);
            }
#pragma unroll
            for (int n = 0; n < 4; ++n) {
                int cn = wn * 64 + n * 16 + (lane & 15);
                int k = kk * 32 + (lane >> 4) * 8;
                int byte = (cn * 128 + k * 2) ^ ((cn & 7) << 4);
                b[n] = *reinterpret_cast<bf16x8*>(reinterpret_cast<char*>(Bs) + byte);
            }
#pragma unroll
            for (int m = 0; m < 4; ++m)
#pragma unroll
                for (int n = 0; n < 4; ++n)
                    acc[m][n] = __builtin_amdgcn_mfma_f32_16x16x32_bf16(a[m], b[n], acc[m][n], 0, 0, 0);
        }
    }
    // C/D layout: col = lane&15, row = (lane>>4)*4 + j
#pragma unroll
    for (int m = 0; m < 4; ++m) {
#pragma unroll
        for (int n = 0; n < 4; ++n) {
            int col = wn * 64 + n * 16 + (lane & 15);
            float bias = fcb[col];
#pragma unroll
            for (int j = 0; j < 4; ++j) {
                int row = row0 + wm * 64 + m * 16 + (lane >> 4) * 4 + j;
                if (row < NROWS)
                    out[(size_t)row * OUTD + col] = fmaxf(acc[m][n][j] + bias, 0.f);
            }
        }
    }
}

extern "C" void kernel_launch(void* const* d_in, const int* in_sizes, int n_in,
                              void* d_out, int out_size, void* d_ws, size_t ws_size,
                              hipStream_t stream) {
    const float* x    = (const float*)d_in[0];
    const float* emb  = (const float*)d_in[1];
    const int*   eidx = (const int*)d_in[2];
    const float* Wq   = (const float*)d_in[3];
    const float* Wk   = (const float*)d_in[4];
    const float* v    = (const float*)d_in[5];
    const float* fcW  = (const float*)d_in[6];
    const float* fcb  = (const float*)d_in[7];
    float* out = (float*)d_out;

    char* ws = (char*)d_ws;
    float* eq          = (float*)ws;                             ws += (size_t)N_NODES * DD * 4;
    float* ek          = (float*)ws;                             ws += (size_t)N_NODES * DD * 4;
    float* exps        = (float*)ws;                             ws += (size_t)N_EDGES * 4;
    float* exps_sorted = (float*)ws;                             ws += (size_t)N_EDGES * 4;
    unsigned short* xb   = (unsigned short*)ws;                  ws += (size_t)NROWS * WFEAT * 2;
    unsigned short* aggb = (unsigned short*)ws;                  ws += (size_t)NROWS * WFEAT * 2;
    unsigned short* fcWb = (unsigned short*)ws;                  ws += (size_t)OUTD * 256 * 2;
    int* deg        = (int*)ws;                                  ws += (size_t)N_NODES * 4;
    int* rowptr     = (int*)ws;                                  ws += (size_t)(N_NODES + 1) * 4 + 12;
    int* cursor     = (int*)ws;                                  ws += (size_t)N_NODES * 4;
    int* bsum       = (int*)ws;                                  ws += 256 * 4;
    int* src_sorted = (int*)ws;

    const int* srcp = eidx;
    const int* dstp = eidx + N_EDGES;

    hipMemsetAsync(deg, 0, (size_t)N_NODES * sizeof(int), stream);

    cvt_bf16_kernel<<<(NROWS * WFEAT / 8 + 255) / 256, 256, 0, stream>>>(x, xb, NROWS * WFEAT / 8);
    cvt_bf16_kernel<<<(OUTD * 256 / 8 + 255) / 256, 256, 0, stream>>>(fcW, fcWb, OUTD * 256 / 8);
    proj_kernel<<<N_NODES * DD / 256, 256, 0, stream>>>(emb, Wq, Wk, eq, ek);
    score_kernel<<<(N_EDGES + 3) / 4, 256, 0, stream>>>(eq, ek, srcp, dstp, v, exps);
    hist_kernel<<<(N_EDGES + 255) / 256, 256, 0, stream>>>(dstp, deg);
    scan_reduce<<<NBLK, SCAN_B, 0, stream>>>(deg, bsum);
    scan_bsum<<<1, 64, 0, stream>>>(bsum);
    scan_final<<<NBLK, SCAN_B, 0, stream>>>(deg, bsum, rowptr, cursor);
    scatter_kernel<<<(N_EDGES + 255) / 256, 256, 0, stream>>>(srcp, dstp, exps, cursor,
                                                              src_sorted, exps_sorted);
    agg_csr_kernel<<<(N_NODES * 64 + 255) / 256, 256, 0, stream>>>(xb, rowptr, src_sorted,
                                                                   exps_sorted, aggb);
    fc_mfma<<<(NROWS + 127) / 128, 256, 0, stream>>>(xb, aggb, fcWb, fcb, out);
}

// Round 5
// 388.518 us; speedup vs baseline: 3.3174x; 1.0753x over previous
//
#include <hip/hip_runtime.h>
#include <hip/hip_bf16.h>
#include <math.h>

#define N_NODES 50000
#define N_EDGES 800000
#define BB 2
#define WFEAT 128
#define DD 64
#define OUTD 128
#define NROWS (BB * N_NODES)      // 100000
#define SCAN_B 256
#define NBLK ((N_NODES + SCAN_B - 1) / SCAN_B)   // 196

typedef __attribute__((ext_vector_type(8))) short bf16x8;
typedef __attribute__((ext_vector_type(4))) float f32x4;
typedef __attribute__((ext_vector_type(8))) unsigned short ushort8;

static __device__ __forceinline__ unsigned short f2bf(float f) {
    __hip_bfloat16 h = __float2bfloat16(f);
    return *reinterpret_cast<unsigned short*>(&h);
}
static __device__ __forceinline__ float bf2f(unsigned short u) {
    unsigned int t = (unsigned int)u << 16;
    return *reinterpret_cast<float*>(&t);
}

// fast tanh: 1 - 2/(exp(2x)+1); exp->inf => 1, exp->0 => -1. ~5 VALU ops.
static __device__ __forceinline__ float tanh_fast(float x) {
    float e = __expf(2.f * x);
    return 1.f - 2.f * __builtin_amdgcn_rcpf(e + 1.f);
}

// ---------------- convert fp32 -> bf16, 8 elems/thread
__global__ void cvt_bf16_kernel(const float* __restrict__ in, unsigned short* __restrict__ out,
                                int n8) {
    int t = blockIdx.x * blockDim.x + threadIdx.x;
    if (t >= n8) return;
    const float4* in4 = (const float4*)in;
    float4 a = in4[2 * t], b = in4[2 * t + 1];
    ushort8 o;
    o[0] = f2bf(a.x); o[1] = f2bf(a.y); o[2] = f2bf(a.z); o[3] = f2bf(a.w);
    o[4] = f2bf(b.x); o[5] = f2bf(b.y); o[6] = f2bf(b.z); o[7] = f2bf(b.w);
    *reinterpret_cast<ushort8*>(&out[8 * t]) = o;
}

// ---------------- Kernel 1: node projections e_q = emb @ Wq^T, e_k = emb @ Wk^T
__global__ __launch_bounds__(256) void proj_kernel(const float* __restrict__ emb,
                                                   const float* __restrict__ Wq,
                                                   const float* __restrict__ Wk,
                                                   float* __restrict__ eq,
                                                   float* __restrict__ ek) {
    __shared__ float wqT[64 * 65];   // wqT[k*65+d] = Wq[d*64+k]
    __shared__ float wkT[64 * 65];
    int tid = threadIdx.x;
    for (int idx = tid; idx < 4096; idx += 256) {
        int d = idx >> 6, k = idx & 63;
        wqT[k * 65 + d] = Wq[idx];
        wkT[k * 65 + d] = Wk[idx];
    }
    __syncthreads();

    int t = blockIdx.x * 256 + tid;          // grid covers N*64 exactly
    int n = t >> 6, d = t & 63;
    const float4* er4 = (const float4*)(emb + (size_t)n * DD);
    float aq = 0.f, ak = 0.f;
#pragma unroll
    for (int k4 = 0; k4 < 16; ++k4) {
        float4 e = er4[k4];
        int k = k4 * 4;
        aq += e.x * wqT[(k + 0) * 65 + d] + e.y * wqT[(k + 1) * 65 + d]
            + e.z * wqT[(k + 2) * 65 + d] + e.w * wqT[(k + 3) * 65 + d];
        ak += e.x * wkT[(k + 0) * 65 + d] + e.y * wkT[(k + 1) * 65 + d]
            + e.z * wkT[(k + 2) * 65 + d] + e.w * wkT[(k + 3) * 65 + d];
    }
    eq[t] = aq;
    ek[t] = ak;
}

// ---------------- Kernel 2: per-edge score -> exp(score)
// (segment_max skipped: |score| <= ||v||_1 ~ 6.4, exp cannot overflow fp32.)
__global__ void score_kernel(const float* __restrict__ eq,
                             const float* __restrict__ ek,
                             const int* __restrict__ src,
                             const int* __restrict__ dst,
                             const float* __restrict__ v,
                             float* __restrict__ exp_s) {
    int wave = (blockIdx.x * blockDim.x + threadIdx.x) >> 6;
    int lane = threadIdx.x & 63;
    if (wave >= N_EDGES) return;
    int s = src[wave], dn = dst[wave];
    float a = eq[(size_t)s * DD + lane] + ek[(size_t)dn * DD + lane];
    float p = tanh_fast(a) * v[lane];
#pragma unroll
    for (int off = 32; off; off >>= 1) p += __shfl_xor(p, off);
    if (lane == 0) exp_s[wave] = __expf(p);
}

// ---------------- CSR build: histogram -> scan -> scatter
__global__ void hist_kernel(const int* __restrict__ dst, int* __restrict__ deg) {
    int e = blockIdx.x * blockDim.x + threadIdx.x;
    if (e < N_EDGES) atomicAdd(&deg[dst[e]], 1);
}

__global__ void scan_reduce(const int* __restrict__ deg, int* __restrict__ bsum) {
    __shared__ int sh[SCAN_B];
    int i = blockIdx.x * SCAN_B + threadIdx.x;
    sh[threadIdx.x] = (i < N_NODES) ? deg[i] : 0;
    __syncthreads();
    for (int s = SCAN_B / 2; s; s >>= 1) {
        if (threadIdx.x < s) sh[threadIdx.x] += sh[threadIdx.x + s];
        __syncthreads();
    }
    if (threadIdx.x == 0) bsum[blockIdx.x] = sh[0];
}

__global__ void scan_bsum(int* __restrict__ bsum) {
    if (threadIdx.x == 0 && blockIdx.x == 0) {
        int acc = 0;
        for (int i = 0; i < NBLK; ++i) { int t = bsum[i]; bsum[i] = acc; acc += t; }
    }
}

__global__ void scan_final(const int* __restrict__ deg, const int* __restrict__ bsum,
                           int* __restrict__ rowptr, int* __restrict__ cursor) {
    __shared__ int sh[SCAN_B];
    int i = blockIdx.x * SCAN_B + threadIdx.x;
    int v = (i < N_NODES) ? deg[i] : 0;
    sh[threadIdx.x] = v;
    __syncthreads();
    for (int s = 1; s < SCAN_B; s <<= 1) {
        int t = 0;
        if ((int)threadIdx.x >= s) t = sh[threadIdx.x - s];
        __syncthreads();
        sh[threadIdx.x] += t;
        __syncthreads();
    }
    if (i < N_NODES) {
        int excl = sh[threadIdx.x] - v + bsum[blockIdx.x];
        rowptr[i] = excl;
        cursor[i] = excl;
        if (i == N_NODES - 1) rowptr[N_NODES] = excl + v;
    }
}

__global__ void scatter_kernel(const int* __restrict__ src, const int* __restrict__ dst,
                               const float* __restrict__ exp_s,
                               int* __restrict__ cursor,
                               int* __restrict__ src_sorted, float* __restrict__ exps_sorted) {
    int e = blockIdx.x * blockDim.x + threadIdx.x;
    if (e >= N_EDGES) return;
    int d = dst[e];
    int pos = atomicAdd(&cursor[d], 1);
    src_sorted[pos] = src[e];
    exps_sorted[pos] = exp_s[e];
}

// ---------------- Kernel 3: CSR aggregation — one wave per dst node, bf16 gathers
__global__ void agg_csr_kernel(const unsigned short* __restrict__ xb,
                               const int* __restrict__ rowptr,
                               const int* __restrict__ src_sorted,
                               const float* __restrict__ exps_sorted,
                               unsigned short* __restrict__ aggb) {
    int node = (blockIdx.x * blockDim.x + threadIdx.x) >> 6;
    int lane = threadIdx.x & 63;
    if (node >= N_NODES) return;
    int p = rowptr[node], end = rowptr[node + 1];
    const unsigned short* x0 = xb;                                // batch 0
    const unsigned short* x1 = xb + (size_t)N_NODES * WFEAT;      // batch 1
    float a0x = 0.f, a0y = 0.f, a1x = 0.f, a1y = 0.f, sum = 0.f;
#pragma unroll 2
    for (; p < end; ++p) {
        int s = src_sorted[p];
        float es = exps_sorted[p];
        sum += es;
        unsigned int u0 = *reinterpret_cast<const unsigned int*>(&x0[(size_t)s * WFEAT + lane * 2]);
        unsigned int u1 = *reinterpret_cast<const unsigned int*>(&x1[(size_t)s * WFEAT + lane * 2]);
        a0x += es * bf2f((unsigned short)u0);
        a0y += es * bf2f((unsigned short)(u0 >> 16));
        a1x += es * bf2f((unsigned short)u1);
        a1y += es * bf2f((unsigned short)(u1 >> 16));
    }
    float inv = 1.f / (sum + 1e-8f);
    unsigned int o0 = (unsigned int)f2bf(a0x * inv) | ((unsigned int)f2bf(a0y * inv) << 16);
    unsigned int o1 = (unsigned int)f2bf(a1x * inv) | ((unsigned int)f2bf(a1y * inv) << 16);
    *reinterpret_cast<unsigned int*>(&aggb[(size_t)node * WFEAT + lane * 2]) = o0;
    *reinterpret_cast<unsigned int*>(&aggb[(size_t)(N_NODES + node) * WFEAT + lane * 2]) = o1;
}

// ---------------- Kernel 4: out = relu([x, agg] @ fcW^T + fcb) via bf16 MFMA
__global__ __launch_bounds__(256) void fc_mfma(const unsigned short* __restrict__ xb,
                                               const unsigned short* __restrict__ aggb,
                                               const unsigned short* __restrict__ fcWb,
                                               const float* __restrict__ fcb,
                                               float* __restrict__ out) {
    __shared__ unsigned short As[128 * 64];   // 16 KB, swizzled [r][k]
    __shared__ unsigned short Bs[128 * 64];   // 16 KB, swizzled [n][k]
    int tid = threadIdx.x;
    int wave = tid >> 6, lane = tid & 63;
    int wm = wave >> 1, wn = wave & 1;
    int row0 = blockIdx.x * 128;

    f32x4 acc[4][4] = {};

    for (int ks = 0; ks < 4; ++ks) {
        const unsigned short* Asrc = (ks < 2) ? xb : aggb;
        int kbase = (ks & 1) * 64;
        __syncthreads();
#pragma unroll
        for (int c = 0; c < 4; ++c) {
            int idx = (c * 256 + tid) * 8;       // element idx in 128x64 tile
            int r = idx >> 6, k = idx & 63;
            int row = row0 + r;
            ulonglong2 val = make_ulonglong2(0ull, 0ull);
            if (row < NROWS)
                val = *reinterpret_cast<const ulonglong2*>(&Asrc[(size_t)row * WFEAT + kbase + k]);
            int byte = (r * 128 + k * 2) ^ ((r & 7) << 4);
            *reinterpret_cast<ulonglong2*>(reinterpret_cast<char*>(As) + byte) = val;

            ulonglong2 wv = *reinterpret_cast<const ulonglong2*>(&fcWb[(size_t)r * 256 + ks * 64 + k]);
            *reinterpret_cast<ulonglong2*>(reinterpret_cast<char*>(Bs) + byte) = wv;
        }
        __syncthreads();
#pragma unroll
        for (int kk = 0; kk < 2; ++kk) {
            bf16x8 a[4], b[4];
#pragma unroll
            for (int m = 0; m < 4; ++m) {
                int r = wm * 64 + m * 16 + (lane & 15);
                int k = kk * 32 + (lane >> 4) * 8;
                int byte = (r * 128 + k * 2) ^ ((r & 7) << 4);
                a[m] = *reinterpret_cast<bf16x8*>(reinterpret_cast<char*>(As) + byte);
            }
#pragma unroll
            for (int n = 0; n < 4; ++n) {
                int cn = wn * 64 + n * 16 + (lane & 15);
                int k = kk * 32 + (lane >> 4) * 8;
                int byte = (cn * 128 + k * 2) ^ ((cn & 7) << 4);
                b[n] = *reinterpret_cast<bf16x8*>(reinterpret_cast<char*>(Bs) + byte);
            }
#pragma unroll
            for (int m = 0; m < 4; ++m)
#pragma unroll
                for (int n = 0; n < 4; ++n)
                    acc[m][n] = __builtin_amdgcn_mfma_f32_16x16x32_bf16(a[m], b[n], acc[m][n], 0, 0, 0);
        }
    }
    // C/D layout: col = lane&15, row = (lane>>4)*4 + j
#pragma unroll
    for (int m = 0; m < 4; ++m) {
#pragma unroll
        for (int n = 0; n < 4; ++n) {
            int col = wn * 64 + n * 16 + (lane & 15);
            float bias = fcb[col];
#pragma unroll
            for (int j = 0; j < 4; ++j) {
                int row = row0 + wm * 64 + m * 16 + (lane >> 4) * 4 + j;
                if (row < NROWS)
                    out[(size_t)row * OUTD + col] = fmaxf(acc[m][n][j] + bias, 0.f);
            }
        }
    }
}

extern "C" void kernel_launch(void* const* d_in, const int* in_sizes, int n_in,
                              void* d_out, int out_size, void* d_ws, size_t ws_size,
                              hipStream_t stream) {
    const float* x    = (const float*)d_in[0];
    const float* emb  = (const float*)d_in[1];
    const int*   eidx = (const int*)d_in[2];
    const float* Wq   = (const float*)d_in[3];
    const float* Wk   = (const float*)d_in[4];
    const float* v    = (const float*)d_in[5];
    const float* fcW  = (const float*)d_in[6];
    const float* fcb  = (const float*)d_in[7];
    float* out = (float*)d_out;

    char* ws = (char*)d_ws;
    float* eq          = (float*)ws;                             ws += (size_t)N_NODES * DD * 4;
    float* ek          = (float*)ws;                             ws += (size_t)N_NODES * DD * 4;
    float* exps        = (float*)ws;                             ws += (size_t)N_EDGES * 4;
    float* exps_sorted = (float*)ws;                             ws += (size_t)N_EDGES * 4;
    unsigned short* xb   = (unsigned short*)ws;                  ws += (size_t)NROWS * WFEAT * 2;
    unsigned short* aggb = (unsigned short*)ws;                  ws += (size_t)NROWS * WFEAT * 2;
    unsigned short* fcWb = (unsigned short*)ws;                  ws += (size_t)OUTD * 256 * 2;
    int* deg        = (int*)ws;                                  ws += (size_t)N_NODES * 4;
    int* rowptr     = (int*)ws;                                  ws += (size_t)(N_NODES + 1) * 4 + 12;
    int* cursor     = (int*)ws;                                  ws += (size_t)N_NODES * 4;
    int* bsum       = (int*)ws;                                  ws += 256 * 4;
    int* src_sorted = (int*)ws;

    const int* srcp = eidx;
    const int* dstp = eidx + N_EDGES;

    hipMemsetAsync(deg, 0, (size_t)N_NODES * sizeof(int), stream);

    cvt_bf16_kernel<<<(NROWS * WFEAT / 8 + 255) / 256, 256, 0, stream>>>(x, xb, NROWS * WFEAT / 8);
    cvt_bf16_kernel<<<(OUTD * 256 / 8 + 255) / 256, 256, 0, stream>>>(fcW, fcWb, OUTD * 256 / 8);
    proj_kernel<<<N_NODES * DD / 256, 256, 0, stream>>>(emb, Wq, Wk, eq, ek);
    score_kernel<<<(N_EDGES + 3) / 4, 256, 0, stream>>>(eq, ek, srcp, dstp, v, exps);
    hist_kernel<<<(N_EDGES + 255) / 256, 256, 0, stream>>>(dstp, deg);
    scan_reduce<<<NBLK, SCAN_B, 0, stream>>>(deg, bsum);
    scan_bsum<<<1, 64, 0, stream>>>(bsum);
    scan_final<<<NBLK, SCAN_B, 0, stream>>>(deg, bsum, rowptr, cursor);
    scatter_kernel<<<(N_EDGES + 255) / 256, 256, 0, stream>>>(srcp, dstp, exps, cursor,
                                                              src_sorted, exps_sorted);
    agg_csr_kernel<<<(N_NODES * 64 + 255) / 256, 256, 0, stream>>>(xb, rowptr, src_sorted,
                                                                   exps_sorted, aggb);
    fc_mfma<<<(NROWS + 127) / 128, 256, 0, stream>>>(xb, aggb, fcWb, fcb, out);
}

// Round 6
// 276.119 us; speedup vs baseline: 4.6679x; 1.4071x over previous
//
#include <hip/hip_runtime.h>
#include <hip/hip_bf16.h>
#include <math.h>

#define N_NODES 50000
#define N_EDGES 800000
#define BB 2
#define WFEAT 128
#define DD 64
#define OUTD 128
#define NROWS (BB * N_NODES)      // 100000
#define SCAN_B 256
#define NBLK ((N_NODES + SCAN_B - 1) / SCAN_B)   // 196

typedef __attribute__((ext_vector_type(8))) short bf16x8;
typedef __attribute__((ext_vector_type(4))) float f32x4;
typedef __attribute__((ext_vector_type(8))) unsigned short ushort8;

static __device__ __forceinline__ unsigned short f2bf(float f) {
    __hip_bfloat16 h = __float2bfloat16(f);
    return *reinterpret_cast<unsigned short*>(&h);
}
static __device__ __forceinline__ float bf2f(unsigned short u) {
    unsigned int t = (unsigned int)u << 16;
    return *reinterpret_cast<float*>(&t);
}

// fast tanh: 1 - 2/(exp(2x)+1); exp->inf => 1, exp->0 => -1. ~5 VALU ops.
static __device__ __forceinline__ float tanh_fast(float x) {
    float e = __expf(2.f * x);
    return 1.f - 2.f * __builtin_amdgcn_rcpf(e + 1.f);
}

// ---------------- convert fp32 -> bf16, 8 elems/thread
__global__ void cvt_bf16_kernel(const float* __restrict__ in, unsigned short* __restrict__ out,
                                int n8) {
    int t = blockIdx.x * blockDim.x + threadIdx.x;
    if (t >= n8) return;
    const float4* in4 = (const float4*)in;
    float4 a = in4[2 * t], b = in4[2 * t + 1];
    ushort8 o;
    o[0] = f2bf(a.x); o[1] = f2bf(a.y); o[2] = f2bf(a.z); o[3] = f2bf(a.w);
    o[4] = f2bf(b.x); o[5] = f2bf(b.y); o[6] = f2bf(b.z); o[7] = f2bf(b.w);
    *reinterpret_cast<ushort8*>(&out[8 * t]) = o;
}

// ---------------- Kernel 1: node projections -> bf16 eq/ek
// Weights staged transposed in LDS (stride 65 breaks bank aliasing); emb row
// comes in as wave-uniform float4 broadcasts. One thread per (node, dim).
__global__ __launch_bounds__(256) void proj_kernel(const float* __restrict__ emb,
                                                   const float* __restrict__ Wq,
                                                   const float* __restrict__ Wk,
                                                   unsigned short* __restrict__ eqb,
                                                   unsigned short* __restrict__ ekb) {
    __shared__ float wqT[64 * 65];   // wqT[k*65+d] = Wq[d*64+k]
    __shared__ float wkT[64 * 65];
    int tid = threadIdx.x;
    for (int idx = tid; idx < 4096; idx += 256) {
        int d = idx >> 6, k = idx & 63;
        wqT[k * 65 + d] = Wq[idx];
        wkT[k * 65 + d] = Wk[idx];
    }
    __syncthreads();

    int t = blockIdx.x * 256 + tid;          // grid covers N*64 exactly
    int n = t >> 6, d = t & 63;
    const float4* er4 = (const float4*)(emb + (size_t)n * DD);
    float aq = 0.f, ak = 0.f;
#pragma unroll
    for (int k4 = 0; k4 < 16; ++k4) {
        float4 e = er4[k4];
        int k = k4 * 4;
        aq += e.x * wqT[(k + 0) * 65 + d] + e.y * wqT[(k + 1) * 65 + d]
            + e.z * wqT[(k + 2) * 65 + d] + e.w * wqT[(k + 3) * 65 + d];
        ak += e.x * wkT[(k + 0) * 65 + d] + e.y * wkT[(k + 1) * 65 + d]
            + e.z * wkT[(k + 2) * 65 + d] + e.w * wkT[(k + 3) * 65 + d];
    }
    eqb[t] = f2bf(aq);
    ekb[t] = f2bf(ak);
}

// ---------------- CSR build: histogram -> scan -> scatter
__global__ void hist_kernel(const int* __restrict__ dst, int* __restrict__ deg) {
    int e = blockIdx.x * blockDim.x + threadIdx.x;
    if (e < N_EDGES) atomicAdd(&deg[dst[e]], 1);
}

__global__ void scan_reduce(const int* __restrict__ deg, int* __restrict__ bsum) {
    __shared__ int sh[SCAN_B];
    int i = blockIdx.x * SCAN_B + threadIdx.x;
    sh[threadIdx.x] = (i < N_NODES) ? deg[i] : 0;
    __syncthreads();
    for (int s = SCAN_B / 2; s; s >>= 1) {
        if (threadIdx.x < s) sh[threadIdx.x] += sh[threadIdx.x + s];
        __syncthreads();
    }
    if (threadIdx.x == 0) bsum[blockIdx.x] = sh[0];
}

__global__ void scan_bsum(int* __restrict__ bsum) {
    if (threadIdx.x == 0 && blockIdx.x == 0) {
        int acc = 0;
        for (int i = 0; i < NBLK; ++i) { int t = bsum[i]; bsum[i] = acc; acc += t; }
    }
}

__global__ void scan_final(const int* __restrict__ deg, const int* __restrict__ bsum,
                           int* __restrict__ rowptr, int* __restrict__ cursor) {
    __shared__ int sh[SCAN_B];
    int i = blockIdx.x * SCAN_B + threadIdx.x;
    int v = (i < N_NODES) ? deg[i] : 0;
    sh[threadIdx.x] = v;
    __syncthreads();
    for (int s = 1; s < SCAN_B; s <<= 1) {
        int t = 0;
        if ((int)threadIdx.x >= s) t = sh[threadIdx.x - s];
        __syncthreads();
        sh[threadIdx.x] += t;
        __syncthreads();
    }
    if (i < N_NODES) {
        int excl = sh[threadIdx.x] - v + bsum[blockIdx.x];
        rowptr[i] = excl;
        cursor[i] = excl;
        if (i == N_NODES - 1) rowptr[N_NODES] = excl + v;
    }
}

__global__ void scatter_kernel(const int* __restrict__ src, const int* __restrict__ dst,
                               int* __restrict__ cursor, int* __restrict__ src_sorted) {
    int e = blockIdx.x * blockDim.x + threadIdx.x;
    if (e >= N_EDGES) return;
    int d = dst[e];
    int pos = atomicAdd(&cursor[d], 1);
    src_sorted[pos] = src[e];
}

// ---------------- Fused score + softmax + aggregation.
// One wave per dst node; 2 edges per iteration (one per 32-lane half).
// Score phase: lane hl holds dims 2hl,2hl+1 (bf16 pair); 5-step shfl reduce.
// Agg phase: lane hl holds feats 4hl..4hl+3 (u64 of 4 bf16) per batch.
// Halves combined at the end with one shfl_xor(·,32).
__global__ __launch_bounds__(256) void agg_fused(const unsigned int* __restrict__ eqb,
                                                 const unsigned int* __restrict__ ekb,
                                                 const float* __restrict__ v,
                                                 const unsigned short* __restrict__ xb,
                                                 const int* __restrict__ rowptr,
                                                 const int* __restrict__ src_sorted,
                                                 unsigned short* __restrict__ aggb) {
    int node = (blockIdx.x * 256 + threadIdx.x) >> 6;
    if (node >= N_NODES) return;
    int lane = threadIdx.x & 63, half = lane >> 5, hl = lane & 31;

    unsigned int eku = ekb[node * 32 + hl];
    float ek0 = bf2f((unsigned short)eku), ek1 = bf2f((unsigned short)(eku >> 16));
    float2 vv = *reinterpret_cast<const float2*>(v + 2 * hl);

    int beg = rowptr[node], end = rowptr[node + 1];
    int nPairs = (end - beg + 1) >> 1;

    float sum = 0.f;
    float a00 = 0.f, a01 = 0.f, a02 = 0.f, a03 = 0.f;
    float a10 = 0.f, a11 = 0.f, a12 = 0.f, a13 = 0.f;

    for (int i = 0; i < nPairs; ++i) {
        int p = beg + 2 * i + half;
        bool valid = p < end;
        int pe = valid ? p : end - 1;
        int s = src_sorted[pe];

        unsigned int equ = eqb[(size_t)s * 32 + hl];
        float t0 = tanh_fast(bf2f((unsigned short)equ) + ek0);
        float t1 = tanh_fast(bf2f((unsigned short)(equ >> 16)) + ek1);
        float t = t0 * vv.x + t1 * vv.y;
#pragma unroll
        for (int off = 16; off; off >>= 1) t += __shfl_xor(t, off);
        float w = valid ? __expf(t) : 0.f;
        sum += w;

        unsigned long long u0 = *reinterpret_cast<const unsigned long long*>(&xb[(size_t)s * WFEAT + 4 * hl]);
        unsigned long long u1 = *reinterpret_cast<const unsigned long long*>(&xb[(size_t)(N_NODES + s) * WFEAT + 4 * hl]);
        a00 += w * bf2f((unsigned short)u0);
        a01 += w * bf2f((unsigned short)(u0 >> 16));
        a02 += w * bf2f((unsigned short)(u0 >> 32));
        a03 += w * bf2f((unsigned short)(u0 >> 48));
        a10 += w * bf2f((unsigned short)u1);
        a11 += w * bf2f((unsigned short)(u1 >> 16));
        a12 += w * bf2f((unsigned short)(u1 >> 32));
        a13 += w * bf2f((unsigned short)(u1 >> 48));
    }

    // combine the two halves
    sum += __shfl_xor(sum, 32);
    a00 += __shfl_xor(a00, 32); a01 += __shfl_xor(a01, 32);
    a02 += __shfl_xor(a02, 32); a03 += __shfl_xor(a03, 32);
    a10 += __shfl_xor(a10, 32); a11 += __shfl_xor(a11, 32);
    a12 += __shfl_xor(a12, 32); a13 += __shfl_xor(a13, 32);

    float inv = 1.f / (sum + 1e-8f);
    float c0 = (half ? a10 : a00) * inv;
    float c1 = (half ? a11 : a01) * inv;
    float c2 = (half ? a12 : a02) * inv;
    float c3 = (half ? a13 : a03) * inv;
    unsigned long long o = (unsigned long long)f2bf(c0)
                         | ((unsigned long long)f2bf(c1) << 16)
                         | ((unsigned long long)f2bf(c2) << 32)
                         | ((unsigned long long)f2bf(c3) << 48);
    size_t row = half ? (size_t)(N_NODES + node) : (size_t)node;
    *reinterpret_cast<unsigned long long*>(&aggb[row * WFEAT + 4 * hl]) = o;
}

// ---------------- Kernel 4: out = relu([x, agg] @ fcW^T + fcb) via bf16 MFMA
__global__ __launch_bounds__(256) void fc_mfma(const unsigned short* __restrict__ xb,
                                               const unsigned short* __restrict__ aggb,
                                               const unsigned short* __restrict__ fcWb,
                                               const float* __restrict__ fcb,
                                               float* __restrict__ out) {
    __shared__ unsigned short As[128 * 64];   // 16 KB, swizzled [r][k]
    __shared__ unsigned short Bs[128 * 64];   // 16 KB, swizzled [n][k]
    int tid = threadIdx.x;
    int wave = tid >> 6, lane = tid & 63;
    int wm = wave >> 1, wn = wave & 1;
    int row0 = blockIdx.x * 128;

    f32x4 acc[4][4] = {};

    for (int ks = 0; ks < 4; ++ks) {
        const unsigned short* Asrc = (ks < 2) ? xb : aggb;
        int kbase = (ks & 1) * 64;
        __syncthreads();
#pragma unroll
        for (int c = 0; c < 4; ++c) {
            int idx = (c * 256 + tid) * 8;       // element idx in 128x64 tile
            int r = idx >> 6, k = idx & 63;
            int row = row0 + r;
            ulonglong2 val = make_ulonglong2(0ull, 0ull);
            if (row < NROWS)
                val = *reinterpret_cast<const ulonglong2*>(&Asrc[(size_t)row * WFEAT + kbase + k]);
            int byte = (r * 128 + k * 2) ^ ((r & 7) << 4);
            *reinterpret_cast<ulonglong2*>(reinterpret_cast<char*>(As) + byte) = val;

            ulonglong2 wv = *reinterpret_cast<const ulonglong2*>(&fcWb[(size_t)r * 256 + ks * 64 + k]);
            *reinterpret_cast<ulonglong2*>(reinterpret_cast<char*>(Bs) + byte) = wv;
        }
        __syncthreads();
#pragma unroll
        for (int kk = 0; kk < 2; ++kk) {
            bf16x8 a[4], b[4];
#pragma unroll
            for (int m = 0; m < 4; ++m) {
                int r = wm * 64 + m * 16 + (lane & 15);
                int k = kk * 32 + (lane >> 4) * 8;
                int byte = (r * 128 + k * 2) ^ ((r & 7) << 4);
                a[m] = *reinterpret_cast<bf16x8*>(reinterpret_cast<char*>(As) + byte);
            }
#pragma unroll
            for (int n = 0; n < 4; ++n) {
                int cn = wn * 64 + n * 16 + (lane & 15);
                int k = kk * 32 + (lane >> 4) * 8;
                int byte = (cn * 128 + k * 2) ^ ((cn & 7) << 4);
                b[n] = *reinterpret_cast<bf16x8*>(reinterpret_cast<char*>(Bs) + byte);
            }
#pragma unroll
            for (int m = 0; m < 4; ++m)
#pragma unroll
                for (int n = 0; n < 4; ++n)
                    acc[m][n] = __builtin_amdgcn_mfma_f32_16x16x32_bf16(a[m], b[n], acc[m][n], 0, 0, 0);
        }
    }
    // C/D layout: col = lane&15, row = (lane>>4)*4 + j
#pragma unroll
    for (int m = 0; m < 4; ++m) {
#pragma unroll
        for (int n = 0; n < 4; ++n) {
            int col = wn * 64 + n * 16 + (lane & 15);
            float bias = fcb[col];
#pragma unroll
            for (int j = 0; j < 4; ++j) {
                int row = row0 + wm * 64 + m * 16 + (lane >> 4) * 4 + j;
                if (row < NROWS)
                    out[(size_t)row * OUTD + col] = fmaxf(acc[m][n][j] + bias, 0.f);
            }
        }
    }
}

extern "C" void kernel_launch(void* const* d_in, const int* in_sizes, int n_in,
                              void* d_out, int out_size, void* d_ws, size_t ws_size,
                              hipStream_t stream) {
    const float* x    = (const float*)d_in[0];
    const float* emb  = (const float*)d_in[1];
    const int*   eidx = (const int*)d_in[2];
    const float* Wq   = (const float*)d_in[3];
    const float* Wk   = (const float*)d_in[4];
    const float* v    = (const float*)d_in[5];
    const float* fcW  = (const float*)d_in[6];
    const float* fcb  = (const float*)d_in[7];
    float* out = (float*)d_out;

    char* ws = (char*)d_ws;
    unsigned short* eqb  = (unsigned short*)ws;                  ws += (size_t)N_NODES * DD * 2;
    unsigned short* ekb  = (unsigned short*)ws;                  ws += (size_t)N_NODES * DD * 2;
    unsigned short* xb   = (unsigned short*)ws;                  ws += (size_t)NROWS * WFEAT * 2;
    unsigned short* aggb = (unsigned short*)ws;                  ws += (size_t)NROWS * WFEAT * 2;
    unsigned short* fcWb = (unsigned short*)ws;                  ws += (size_t)OUTD * 256 * 2;
    int* deg        = (int*)ws;                                  ws += (size_t)N_NODES * 4;
    int* rowptr     = (int*)ws;                                  ws += (size_t)(N_NODES + 1) * 4 + 12;
    int* cursor     = (int*)ws;                                  ws += (size_t)N_NODES * 4;
    int* bsum       = (int*)ws;                                  ws += 256 * 4;
    int* src_sorted = (int*)ws;

    const int* srcp = eidx;
    const int* dstp = eidx + N_EDGES;

    hipMemsetAsync(deg, 0, (size_t)N_NODES * sizeof(int), stream);

    cvt_bf16_kernel<<<(NROWS * WFEAT / 8 + 255) / 256, 256, 0, stream>>>(x, xb, NROWS * WFEAT / 8);
    cvt_bf16_kernel<<<(OUTD * 256 / 8 + 255) / 256, 256, 0, stream>>>(fcW, fcWb, OUTD * 256 / 8);
    proj_kernel<<<N_NODES * DD / 256, 256, 0, stream>>>(emb, Wq, Wk, eqb, ekb);
    hist_kernel<<<(N_EDGES + 255) / 256, 256, 0, stream>>>(dstp, deg);
    scan_reduce<<<NBLK, SCAN_B, 0, stream>>>(deg, bsum);
    scan_bsum<<<1, 64, 0, stream>>>(bsum);
    scan_final<<<NBLK, SCAN_B, 0, stream>>>(deg, bsum, rowptr, cursor);
    scatter_kernel<<<(N_EDGES + 255) / 256, 256, 0, stream>>>(srcp, dstp, cursor, src_sorted);
    agg_fused<<<(N_NODES * 64 + 255) / 256, 256, 0, stream>>>((const unsigned int*)eqb,
                                                              (const unsigned int*)ekb,
                                                              v, xb, rowptr, src_sorted, aggb);
    fc_mfma<<<(NROWS + 127) / 128, 256, 0, stream>>>(xb, aggb, fcWb, fcb, out);
}

// Round 7
// 254.826 us; speedup vs baseline: 5.0579x; 1.0836x over previous
//
#include <hip/hip_runtime.h>
#include <hip/hip_bf16.h>
#include <math.h>

#define N_NODES 50000
#define N_EDGES 800000
#define BB 2
#define WFEAT 128
#define DD 64
#define OUTD 128
#define NROWS (BB * N_NODES)      // 100000
#define SCAN_B 256
#define NBLK ((N_NODES + SCAN_B - 1) / SCAN_B)   // 196

typedef __attribute__((ext_vector_type(8))) short bf16x8;
typedef __attribute__((ext_vector_type(4))) float f32x4;
typedef __attribute__((ext_vector_type(8))) unsigned short ushort8;

#define PRESCALE 2.8853900817779268f   // 2*log2(e)
#define L2E 1.4426950408889634f

static __device__ __forceinline__ unsigned short f2bf(float f) {
    __hip_bfloat16 h = __float2bfloat16(f);
    return *reinterpret_cast<unsigned short*>(&h);
}
static __device__ __forceinline__ float bf_lo(unsigned int w) {
    return __uint_as_float(w << 16);
}
static __device__ __forceinline__ float bf_hi(unsigned int w) {
    return __uint_as_float(w & 0xFFFF0000u);
}
// 2^x via single HW instruction (v_exp_f32)
static __device__ __forceinline__ float exp2_hw(float x) {
    float r;
    asm("v_exp_f32 %0, %1" : "=v"(r) : "v"(x));
    return r;
}

// ---------------- convert fp32 -> bf16, 8 elems/thread
__global__ void cvt_bf16_kernel(const float* __restrict__ in, unsigned short* __restrict__ out,
                                int n8) {
    int t = blockIdx.x * blockDim.x + threadIdx.x;
    if (t >= n8) return;
    const float4* in4 = (const float4*)in;
    float4 a = in4[2 * t], b = in4[2 * t + 1];
    ushort8 o;
    o[0] = f2bf(a.x); o[1] = f2bf(a.y); o[2] = f2bf(a.z); o[3] = f2bf(a.w);
    o[4] = f2bf(b.x); o[5] = f2bf(b.y); o[6] = f2bf(b.z); o[7] = f2bf(b.w);
    *reinterpret_cast<ushort8*>(&out[8 * t]) = o;
}

// ---------------- Kernel 1: node projections -> bf16 eq/ek, PRESCALED by 2*log2e
// so that exp(2a) == exp2(eq2[s]+ek2[d]) downstream.
__global__ __launch_bounds__(256) void proj_kernel(const float* __restrict__ emb,
                                                   const float* __restrict__ Wq,
                                                   const float* __restrict__ Wk,
                                                   unsigned short* __restrict__ eqb,
                                                   unsigned short* __restrict__ ekb) {
    __shared__ float wqT[64 * 65];   // wqT[k*65+d] = Wq[d*64+k]
    __shared__ float wkT[64 * 65];
    int tid = threadIdx.x;
    for (int idx = tid; idx < 4096; idx += 256) {
        int d = idx >> 6, k = idx & 63;
        wqT[k * 65 + d] = Wq[idx];
        wkT[k * 65 + d] = Wk[idx];
    }
    __syncthreads();

    int t = blockIdx.x * 256 + tid;          // grid covers N*64 exactly
    int n = t >> 6, d = t & 63;
    const float4* er4 = (const float4*)(emb + (size_t)n * DD);
    float aq = 0.f, ak = 0.f;
#pragma unroll
    for (int k4 = 0; k4 < 16; ++k4) {
        float4 e = er4[k4];
        int k = k4 * 4;
        aq += e.x * wqT[(k + 0) * 65 + d] + e.y * wqT[(k + 1) * 65 + d]
            + e.z * wqT[(k + 2) * 65 + d] + e.w * wqT[(k + 3) * 65 + d];
        ak += e.x * wkT[(k + 0) * 65 + d] + e.y * wkT[(k + 1) * 65 + d]
            + e.z * wkT[(k + 2) * 65 + d] + e.w * wkT[(k + 3) * 65 + d];
    }
    eqb[t] = f2bf(PRESCALE * aq);
    ekb[t] = f2bf(PRESCALE * ak);
}

// ---------------- CSR build: histogram -> scan -> scatter
__global__ void hist_kernel(const int* __restrict__ dst, int* __restrict__ deg) {
    int e = blockIdx.x * blockDim.x + threadIdx.x;
    if (e < N_EDGES) atomicAdd(&deg[dst[e]], 1);
}

__global__ void scan_reduce(const int* __restrict__ deg, int* __restrict__ bsum) {
    __shared__ int sh[SCAN_B];
    int i = blockIdx.x * SCAN_B + threadIdx.x;
    sh[threadIdx.x] = (i < N_NODES) ? deg[i] : 0;
    __syncthreads();
    for (int s = SCAN_B / 2; s; s >>= 1) {
        if (threadIdx.x < s) sh[threadIdx.x] += sh[threadIdx.x + s];
        __syncthreads();
    }
    if (threadIdx.x == 0) bsum[blockIdx.x] = sh[0];
}

// parallel exclusive scan over NBLK block sums (single 256-thread block)
__global__ void scan_bsum(int* __restrict__ bsum) {
    __shared__ int sh[SCAN_B];
    int tid = threadIdx.x;
    int v = (tid < NBLK) ? bsum[tid] : 0;
    sh[tid] = v;
    __syncthreads();
    for (int s = 1; s < SCAN_B; s <<= 1) {
        int t = (tid >= s) ? sh[tid - s] : 0;
        __syncthreads();
        sh[tid] += t;
        __syncthreads();
    }
    if (tid < NBLK) bsum[tid] = sh[tid] - v;   // exclusive
}

__global__ void scan_final(const int* __restrict__ deg, const int* __restrict__ bsum,
                           int* __restrict__ rowptr, int* __restrict__ cursor) {
    __shared__ int sh[SCAN_B];
    int i = blockIdx.x * SCAN_B + threadIdx.x;
    int v = (i < N_NODES) ? deg[i] : 0;
    sh[threadIdx.x] = v;
    __syncthreads();
    for (int s = 1; s < SCAN_B; s <<= 1) {
        int t = 0;
        if ((int)threadIdx.x >= s) t = sh[threadIdx.x - s];
        __syncthreads();
        sh[threadIdx.x] += t;
        __syncthreads();
    }
    if (i < N_NODES) {
        int excl = sh[threadIdx.x] - v + bsum[blockIdx.x];
        rowptr[i] = excl;
        cursor[i] = excl;
        if (i == N_NODES - 1) rowptr[N_NODES] = excl + v;
    }
}

__global__ void scatter_kernel(const int* __restrict__ src, const int* __restrict__ dst,
                               int* __restrict__ cursor, int* __restrict__ src_sorted) {
    int e = blockIdx.x * blockDim.x + threadIdx.x;
    if (e >= N_EDGES) return;
    int d = dst[e];
    int pos = atomicAdd(&cursor[d], 1);
    src_sorted[pos] = src[e];
}

// ---------------- Fused score + softmax + aggregation.
// One wave per dst node; 4 edges per iteration, one per 16-lane group.
// Score: lane hl handles dims 4hl..4hl+3; Σv·tanh = Vtot − 2Σv·r with
// r = 1/(exp2(eq2+ek2)+1); 4-step shfl reduce within the group.
// Agg: lane hl holds feats 8hl..8hl+7 (16B) per batch; groups combined at end
// with shfl_xor(16) + shfl_xor(32). Groups 0/1 write batch0/batch1.
__global__ __launch_bounds__(256) void agg_fused(const unsigned short* __restrict__ eqb,
                                                 const unsigned short* __restrict__ ekb,
                                                 const float* __restrict__ v,
                                                 const unsigned short* __restrict__ xb,
                                                 const int* __restrict__ rowptr,
                                                 const int* __restrict__ src_sorted,
                                                 unsigned short* __restrict__ aggb) {
    int node = (blockIdx.x * 256 + threadIdx.x) >> 6;
    if (node >= N_NODES) return;
    int lane = threadIdx.x & 63;
    int g = lane >> 4, hl = lane & 15;

    uint2 eku = *reinterpret_cast<const uint2*>(ekb + (size_t)node * DD + 4 * hl);
    float k0 = bf_lo(eku.x), k1 = bf_hi(eku.x), k2 = bf_lo(eku.y), k3 = bf_hi(eku.y);
    float4 vv = *reinterpret_cast<const float4*>(v + 4 * hl);
    float vs = vv.x + vv.y + vv.z + vv.w;
    vs += __shfl_xor(vs, 1); vs += __shfl_xor(vs, 2);
    vs += __shfl_xor(vs, 4); vs += __shfl_xor(vs, 8);
    float vtotl2 = vs * L2E;

    int beg = rowptr[node], end = rowptr[node + 1];
    int nIter = (end - beg + 3) >> 2;

    float sum = 0.f;
    float a0[8] = {}, a1[8] = {};

    for (int i = 0; i < nIter; ++i) {
        int p = beg + 4 * i + g;
        bool valid = p < end;
        int pe = valid ? p : end - 1;
        int s = src_sorted[pe];

        uint2 equ = *reinterpret_cast<const uint2*>(eqb + (size_t)s * DD + 4 * hl);
        float s0 = bf_lo(equ.x) + k0, s1 = bf_hi(equ.x) + k1;
        float s2 = bf_lo(equ.y) + k2, s3 = bf_hi(equ.y) + k3;
        float r =      vv.x * __builtin_amdgcn_rcpf(exp2_hw(s0) + 1.f);
        r = fmaf(vv.y, __builtin_amdgcn_rcpf(exp2_hw(s1) + 1.f), r);
        r = fmaf(vv.z, __builtin_amdgcn_rcpf(exp2_hw(s2) + 1.f), r);
        r = fmaf(vv.w, __builtin_amdgcn_rcpf(exp2_hw(s3) + 1.f), r);
        r += __shfl_xor(r, 1); r += __shfl_xor(r, 2);
        r += __shfl_xor(r, 4); r += __shfl_xor(r, 8);
        float w = exp2_hw(fmaf(-2.f * L2E, r, vtotl2));
        w = valid ? w : 0.f;
        sum += w;

        uint4 u0 = *reinterpret_cast<const uint4*>(xb + (size_t)s * WFEAT + 8 * hl);
        uint4 u1 = *reinterpret_cast<const uint4*>(xb + (size_t)(N_NODES + s) * WFEAT + 8 * hl);
        a0[0] = fmaf(w, bf_lo(u0.x), a0[0]); a0[1] = fmaf(w, bf_hi(u0.x), a0[1]);
        a0[2] = fmaf(w, bf_lo(u0.y), a0[2]); a0[3] = fmaf(w, bf_hi(u0.y), a0[3]);
        a0[4] = fmaf(w, bf_lo(u0.z), a0[4]); a0[5] = fmaf(w, bf_hi(u0.z), a0[5]);
        a0[6] = fmaf(w, bf_lo(u0.w), a0[6]); a0[7] = fmaf(w, bf_hi(u0.w), a0[7]);
        a1[0] = fmaf(w, bf_lo(u1.x), a1[0]); a1[1] = fmaf(w, bf_hi(u1.x), a1[1]);
        a1[2] = fmaf(w, bf_lo(u1.y), a1[2]); a1[3] = fmaf(w, bf_hi(u1.y), a1[3]);
        a1[4] = fmaf(w, bf_lo(u1.z), a1[4]); a1[5] = fmaf(w, bf_hi(u1.z), a1[5]);
        a1[6] = fmaf(w, bf_lo(u1.w), a1[6]); a1[7] = fmaf(w, bf_hi(u1.w), a1[7]);
    }

    // combine the four 16-lane groups
    sum += __shfl_xor(sum, 16); sum += __shfl_xor(sum, 32);
#pragma unroll
    for (int j = 0; j < 8; ++j) {
        a0[j] += __shfl_xor(a0[j], 16); a0[j] += __shfl_xor(a0[j], 32);
        a1[j] += __shfl_xor(a1[j], 16); a1[j] += __shfl_xor(a1[j], 32);
    }
    float inv = __builtin_amdgcn_rcpf(sum + 1e-8f);

    if (g < 2) {
        // per-element selects keep a0/a1 in registers (no runtime array indexing)
        float c0 = (g ? a1[0] : a0[0]) * inv, c1 = (g ? a1[1] : a0[1]) * inv;
        float c2 = (g ? a1[2] : a0[2]) * inv, c3 = (g ? a1[3] : a0[3]) * inv;
        float c4 = (g ? a1[4] : a0[4]) * inv, c5 = (g ? a1[5] : a0[5]) * inv;
        float c6 = (g ? a1[6] : a0[6]) * inv, c7 = (g ? a1[7] : a0[7]) * inv;
        uint4 o;
        o.x = (unsigned int)f2bf(c0) | ((unsigned int)f2bf(c1) << 16);
        o.y = (unsigned int)f2bf(c2) | ((unsigned int)f2bf(c3) << 16);
        o.z = (unsigned int)f2bf(c4) | ((unsigned int)f2bf(c5) << 16);
        o.w = (unsigned int)f2bf(c6) | ((unsigned int)f2bf(c7) << 16);
        size_t row = g ? (size_t)(N_NODES + node) : (size_t)node;
        *reinterpret_cast<uint4*>(&aggb[row * WFEAT + 8 * hl]) = o;
    }
}

// ---------------- Kernel 4: out = relu([x, agg] @ fcW^T + fcb) via bf16 MFMA
__global__ __launch_bounds__(256) void fc_mfma(const unsigned short* __restrict__ xb,
                                               const unsigned short* __restrict__ aggb,
                                               const unsigned short* __restrict__ fcWb,
                                               const float* __restrict__ fcb,
                                               float* __restrict__ out) {
    __shared__ unsigned short As[128 * 64];   // 16 KB, swizzled [r][k]
    __shared__ unsigned short Bs[128 * 64];   // 16 KB, swizzled [n][k]
    int tid = threadIdx.x;
    int wave = tid >> 6, lane = tid & 63;
    int wm = wave >> 1, wn = wave & 1;
    int row0 = blockIdx.x * 128;

    f32x4 acc[4][4] = {};

    for (int ks = 0; ks < 4; ++ks) {
        const unsigned short* Asrc = (ks < 2) ? xb : aggb;
        int kbase = (ks & 1) * 64;
        __syncthreads();
#pragma unroll
        for (int c = 0; c < 4; ++c) {
            int idx = (c * 256 + tid) * 8;       // element idx in 128x64 tile
            int r = idx >> 6, k = idx & 63;
            int row = row0 + r;
            ulonglong2 val = make_ulonglong2(0ull, 0ull);
            if (row < NROWS)
                val = *reinterpret_cast<const ulonglong2*>(&Asrc[(size_t)row * WFEAT + kbase + k]);
            int byte = (r * 128 + k * 2) ^ ((r & 7) << 4);
            *reinterpret_cast<ulonglong2*>(reinterpret_cast<char*>(As) + byte) = val;

            ulonglong2 wv = *reinterpret_cast<const ulonglong2*>(&fcWb[(size_t)r * 256 + ks * 64 + k]);
            *reinterpret_cast<ulonglong2*>(reinterpret_cast<char*>(Bs) + byte) = wv;
        }
        __syncthreads();
#pragma unroll
        for (int kk = 0; kk < 2; ++kk) {
            bf16x8 a[4], b[4];
#pragma unroll
            for (int m = 0; m < 4; ++m) {
                int r = wm * 64 + m * 16 + (lane & 15);
                int k = kk * 32 + (lane >> 4) * 8;
                int byte = (r * 128 + k * 2) ^ ((r & 7) << 4);
                a[m] = *reinterpret_cast<bf16x8*>(reinterpret_cast<char*>(As) + byte);
            }
#pragma unroll
            for (int n = 0; n < 4; ++n) {
                int cn = wn * 64 + n * 16 + (lane & 15);
                int k = kk * 32 + (lane >> 4) * 8;
                int byte = (cn * 128 + k * 2) ^ ((cn & 7) << 4);
                b[n] = *reinterpret_cast<bf16x8*>(reinterpret_cast<char*>(Bs) + byte);
            }
#pragma unroll
            for (int m = 0; m < 4; ++m)
#pragma unroll
                for (int n = 0; n < 4; ++n)
                    acc[m][n] = __builtin_amdgcn_mfma_f32_16x16x32_bf16(a[m], b[n], acc[m][n], 0, 0, 0);
        }
    }
    // C/D layout: col = lane&15, row = (lane>>4)*4 + j
#pragma unroll
    for (int m = 0; m < 4; ++m) {
#pragma unroll
        for (int n = 0; n < 4; ++n) {
            int col = wn * 64 + n * 16 + (lane & 15);
            float bias = fcb[col];
#pragma unroll
            for (int j = 0; j < 4; ++j) {
                int row = row0 + wm * 64 + m * 16 + (lane >> 4) * 4 + j;
                if (row < NROWS)
                    out[(size_t)row * OUTD + col] = fmaxf(acc[m][n][j] + bias, 0.f);
            }
        }
    }
}

extern "C" void kernel_launch(void* const* d_in, const int* in_sizes, int n_in,
                              void* d_out, int out_size, void* d_ws, size_t ws_size,
                              hipStream_t stream) {
    const float* x    = (const float*)d_in[0];
    const float* emb  = (const float*)d_in[1];
    const int*   eidx = (const int*)d_in[2];
    const float* Wq   = (const float*)d_in[3];
    const float* Wk   = (const float*)d_in[4];
    const float* v    = (const float*)d_in[5];
    const float* fcW  = (const float*)d_in[6];
    const float* fcb  = (const float*)d_in[7];
    float* out = (float*)d_out;

    char* ws = (char*)d_ws;
    unsigned short* eqb  = (unsigned short*)ws;                  ws += (size_t)N_NODES * DD * 2;
    unsigned short* ekb  = (unsigned short*)ws;                  ws += (size_t)N_NODES * DD * 2;
    unsigned short* xb   = (unsigned short*)ws;                  ws += (size_t)NROWS * WFEAT * 2;
    unsigned short* aggb = (unsigned short*)ws;                  ws += (size_t)NROWS * WFEAT * 2;
    unsigned short* fcWb = (unsigned short*)ws;                  ws += (size_t)OUTD * 256 * 2;
    int* deg        = (int*)ws;                                  ws += (size_t)N_NODES * 4;
    int* rowptr     = (int*)ws;                                  ws += (size_t)(N_NODES + 1) * 4 + 12;
    int* cursor     = (int*)ws;                                  ws += (size_t)N_NODES * 4;
    int* bsum       = (int*)ws;                                  ws += 256 * 4;
    int* src_sorted = (int*)ws;

    const int* srcp = eidx;
    const int* dstp = eidx + N_EDGES;

    hipMemsetAsync(deg, 0, (size_t)N_NODES * sizeof(int), stream);

    cvt_bf16_kernel<<<(NROWS * WFEAT / 8 + 255) / 256, 256, 0, stream>>>(x, xb, NROWS * WFEAT / 8);
    cvt_bf16_kernel<<<(OUTD * 256 / 8 + 255) / 256, 256, 0, stream>>>(fcW, fcWb, OUTD * 256 / 8);
    proj_kernel<<<N_NODES * DD / 256, 256, 0, stream>>>(emb, Wq, Wk, eqb, ekb);
    hist_kernel<<<(N_EDGES + 255) / 256, 256, 0, stream>>>(dstp, deg);
    scan_reduce<<<NBLK, SCAN_B, 0, stream>>>(deg, bsum);
    scan_bsum<<<1, SCAN_B, 0, stream>>>(bsum);
    scan_final<<<NBLK, SCAN_B, 0, stream>>>(deg, bsum, rowptr, cursor);
    scatter_kernel<<<(N_EDGES + 255) / 256, 256, 0, stream>>>(srcp, dstp, cursor, src_sorted);
    agg_fused<<<(N_NODES * 64 + 255) / 256, 256, 0, stream>>>(eqb, ekb, v, xb, rowptr,
                                                              src_sorted, aggb);
    fc_mfma<<<(NROWS + 127) / 128, 256, 0, stream>>>(xb, aggb, fcWb, fcb, out);
}